// Round 9
// baseline (433.282 us; speedup 1.0000x reference)
//
#include <hip/hip_runtime.h>
#include <math.h>

#define CI 256
#define CO 256
#define HWN 4096  // H*W

typedef short bf16x8 __attribute__((ext_vector_type(8)));
typedef float f32x4 __attribute__((ext_vector_type(4)));

__device__ inline unsigned pk2(float a, float b) {  // RNE pack 2 f32 -> 2 bf16
  unsigned ua = __float_as_uint(a), ub = __float_as_uint(b);
  ua += 0x7fff + ((ua >> 16) & 1);
  ub += 0x7fff + ((ub >> 16) & 1);
  return (ua >> 16) | (ub & 0xffff0000u);
}

// Raw barrier that does NOT drain vmcnt (keeps prefetch loads in flight).
#define PIPE_BARRIER()                                    \
  do {                                                    \
    __builtin_amdgcn_sched_barrier(0);                    \
    asm volatile("s_waitcnt lgkmcnt(0)" ::: "memory");    \
    __builtin_amdgcn_s_barrier();                         \
    __builtin_amdgcn_sched_barrier(0);                    \
  } while (0)

// ---------------------------------------------------------------------------
// Kernel 0: weight pre-transpose+convert: w[o][c][tap] f32 -> wT[tap][o][c] bf16
// ---------------------------------------------------------------------------
__global__ __launch_bounds__(256) void k_wprep(const float* __restrict__ wgt,
                                               unsigned short* __restrict__ wT) {
  const int o = blockIdx.x, c = threadIdx.x;
  const float* wp = wgt + o * 2304 + c * 9;
  float v[9];
#pragma unroll
  for (int t = 0; t < 9; ++t) v[t] = wp[t];
#pragma unroll
  for (int t = 0; t < 9; ++t) {
    unsigned u = __float_as_uint(v[t]);
    u += 0x7fff + ((u >> 16) & 1);
    wT[(t << 16) + (o << 8) + c] = (unsigned short)(u >> 16);
  }
}

// ---------------------------------------------------------------------------
// Kernel 1: offset (18ch) + modulation (9ch) 3x3 conv over Ci=256. R5-exact.
// ---------------------------------------------------------------------------
__global__ __launch_bounds__(512, 4) void k_offmod(
    const float* __restrict__ x, const float* __restrict__ ow,
    const float* __restrict__ ob, const float* __restrict__ mw,
    const float* __restrict__ mb, float* __restrict__ dyb,
    float* __restrict__ dxb, float* __restrict__ mskb) {
  __shared__ float xs[1584];   // 8 ch * 3 rows * 66 cols
  __shared__ float ps[13824];  // 64 px * 27 ch * 8 groups
  const int tid = threadIdx.x;
  const int bh = blockIdx.x;
  const int b = bh >> 6, h = bh & 63;
  const int cg = __builtin_amdgcn_readfirstlane(tid >> 6);  // wave id 0..7
  const int px = tid & 63;
  float acc[27];
#pragma unroll
  for (int i = 0; i < 27; ++i) acc[i] = 0.f;
  const float* xb = x + b * (CI * HWN);
  for (int t = 0; t < 32; ++t) {
    __syncthreads();
    for (int i = tid; i < 1584; i += 512) {
      int cl = i / 198;
      int rem = i - cl * 198;
      int r = rem / 66;
      int col = rem - r * 66 - 1;
      int hh = h - 1 + r;
      float v = 0.f;
      if (hh >= 0 && hh < 64 && col >= 0 && col < 64)
        v = xb[(8 * t + cl) * HWN + hh * 64 + col];
      xs[i] = v;
    }
    __syncthreads();
    float xv[9];
#pragma unroll
    for (int r = 0; r < 3; ++r)
#pragma unroll
      for (int kx = 0; kx < 3; ++kx)
        xv[r * 3 + kx] = xs[cg * 198 + r * 66 + px + kx];
    const int c = 8 * t + cg;
    const float* owp = ow + c * 9;
    const float* mwp = mw + c * 9;
#pragma unroll
    for (int ch = 0; ch < 18; ++ch)
#pragma unroll
      for (int k = 0; k < 9; ++k)
        acc[ch] = fmaf(owp[ch * 2304 + k], xv[k], acc[ch]);
#pragma unroll
    for (int ch = 0; ch < 9; ++ch)
#pragma unroll
      for (int k = 0; k < 9; ++k)
        acc[18 + ch] = fmaf(mwp[ch * 2304 + k], xv[k], acc[18 + ch]);
  }
  __syncthreads();
#pragma unroll
  for (int ch = 0; ch < 27; ++ch) ps[(px * 27 + ch) * 8 + cg] = acc[ch];
  __syncthreads();
  for (int i = tid; i < 1728; i += 512) {
    int p2 = i / 27;
    int ch = i - p2 * 27;
    float s = 0.f;
#pragma unroll
    for (int g = 0; g < 8; ++g) s += ps[i * 8 + g];
    if (ch < 18) {
      s += ob[ch];
      int k = ch >> 1;
      int o9 = ((b * 9 + k) << 12) + (h << 6) + p2;
      if ((ch & 1) == 0) dyb[o9] = s;
      else dxb[o9] = s;
    } else {
      int k = ch - 18;
      s += mb[k];
      mskb[((b * 9 + k) << 12) + (h << 6) + p2] = 2.f / (1.f + expf(-s));
    }
  }
}

// ---------------------------------------------------------------------------
// Kernel 2: bf16-MFMA gather-GEMM. R8 dataflow, reshaped for barrier-domain
// parallelism: 256 thr / 4 waves per block, 32 px (half-row) x 256 out,
// grid 1024 -> 4 independent blocks/CU (vs R8's 2x8-wave lockstep).
// b = bid&7 pins each XCD to one image (slab+wT < 4MB L2).
// Wave wv owns o in [wv*64, wv*64+64) (4 nfrag); M = 32 px (2 mfrag).
// A: all 256 threads stage 32px x 64ch into swizzled sA (thread t: px=t&31,
// ch=(t>>5)*8) with 1-chunk register prefetch across PIPE_BARRIER.
// B: direct 16B register loads from wT (R8-proven addressing, wv width 64).
// Epilogue: direct coalesced-64B-line stores (D: o=lane&15-col, px rows).
// ---------------------------------------------------------------------------
__global__ __launch_bounds__(256, 4) void k_main(
    const float* __restrict__ x, const unsigned short* __restrict__ wT,
    const float* __restrict__ dyb, const float* __restrict__ dxb,
    const float* __restrict__ mskb, float* __restrict__ out,
    float* __restrict__ psum, float* __restrict__ psq) {
  __shared__ __align__(16) uint2 s_cw[288];   // [9][32] 4x bf16 corner w
  __shared__ ushort4 s_ci[288];               // [9][32] corner idx
  __shared__ __align__(16) char sA[8192];     // 32px x 64ch bf16, swizzled

  const int tid = threadIdx.x;
  const int bid = blockIdx.x;   // 1024 blocks
  const int b = bid & 7;        // XCD-pinned image
  const int r2 = bid >> 3;      // 0..127
  const int h = r2 >> 1;
  const int half = r2 & 1;
  const int lane = tid & 63;
  const int wv = tid >> 6;      // 0..3

  // ---- corner table: 9 taps * 32 px ----
  for (int i = tid; i < 288; i += 256) {
    int k = i >> 5, pxi = i & 31;
    int px_w = (half << 5) + pxi;
    int o9 = ((b * 9 + k) << 12) + (h << 6) + px_w;
    float m = mskb[o9];
    float py = (float)(h - 1 + k / 3) + dyb[o9];
    float pxf = (float)(px_w - 1 + k % 3) + dxb[o9];
    float y0f = floorf(py), x0f = floorf(pxf);
    float wy = py - y0f, wx = pxf - x0f;
    int y0 = (int)y0f, x0 = (int)x0f;
    int y1 = y0 + 1, x1 = x0 + 1;
    float w00 = (1.f - wy) * (1.f - wx) * m;
    float w01 = (1.f - wy) * wx * m;
    float w10 = wy * (1.f - wx) * m;
    float w11 = wy * wx * m;
    bool vy0 = ((unsigned)y0 < 64u), vy1 = ((unsigned)y1 < 64u);
    bool vx0 = ((unsigned)x0 < 64u), vx1 = ((unsigned)x1 < 64u);
    if (!(vy0 && vx0)) w00 = 0.f;
    if (!(vy0 && vx1)) w01 = 0.f;
    if (!(vy1 && vx0)) w10 = 0.f;
    if (!(vy1 && vx1)) w11 = 0.f;
    int y0c = min(max(y0, 0), 63), y1c = min(max(y1, 0), 63);
    int x0c = min(max(x0, 0), 63), x1c = min(max(x1, 0), 63);
    s_cw[i] = make_uint2(pk2(w00, w01), pk2(w10, w11));
    s_ci[i] = make_ushort4((unsigned short)(y0c * 64 + x0c),
                           (unsigned short)(y0c * 64 + x1c),
                           (unsigned short)(y1c * 64 + x0c),
                           (unsigned short)(y1c * 64 + x1c));
  }
  __syncthreads();

  f32x4 acc[2][4];
#pragma unroll
  for (int mf = 0; mf < 2; ++mf)
#pragma unroll
    for (int nf = 0; nf < 4; ++nf) acc[mf][nf] = (f32x4){0.f, 0.f, 0.f, 0.f};

  const float* xb = x + b * (CI * HWN);
  const int pxs = tid & 31;   // staged pixel
  const int cgs = tid >> 5;   // staged 8-ch group 0..7
  const int aslot = (pxs << 7) + ((cgs ^ (pxs & 7)) << 4);
  const int ctab = pxs;       // corner table column

  // ---- prologue: corner regs + A-prefetch for chunk 0 (cq=0, tap=0) ----
  float rx[32];
  float4 cwC;
  {
    uint2 p = s_cw[ctab];
    cwC.x = __uint_as_float(p.x << 16);
    cwC.y = __uint_as_float(p.x & 0xffff0000u);
    cwC.z = __uint_as_float(p.y << 16);
    cwC.w = __uint_as_float(p.y & 0xffff0000u);
    ushort4 ci0 = s_ci[ctab];
    const float* xpn = xb + (cgs << 3) * HWN;
#pragma unroll
    for (int s = 0; s < 8; ++s) {
      const float* xp = xpn + s * HWN;
      rx[4 * s + 0] = xp[ci0.x];
      rx[4 * s + 1] = xp[ci0.y];
      rx[4 * s + 2] = xp[ci0.z];
      rx[4 * s + 3] = xp[ci0.w];
    }
  }

#pragma unroll 1
  for (int t = 0; t < 36; ++t) {
    const int cq = t / 9;
    const int tap = t - cq * 9;
    // ---- B: direct 16B fragment loads into registers (L2-resident wT) ----
    const unsigned short* wb0 = wT + (tap << 16) +
                                (((wv << 6) + (lane & 15)) << 8) + (cq << 6) +
                                ((lane >> 4) << 3);
    bf16x8 rb[4][2];
#pragma unroll
    for (int nf = 0; nf < 4; ++nf)
#pragma unroll
      for (int ks = 0; ks < 2; ++ks)
        rb[nf][ks] = *(const bf16x8*)(wb0 + (nf << 12) + (ks << 5));
    // ---- pack chunk t's prefetched x-values -> sA ----
    {
      unsigned pkv[4];
#pragma unroll
      for (int j2 = 0; j2 < 4; ++j2) {
        float v0 = cwC.x * rx[8 * j2 + 0];
        v0 = fmaf(cwC.y, rx[8 * j2 + 1], v0);
        v0 = fmaf(cwC.z, rx[8 * j2 + 2], v0);
        v0 = fmaf(cwC.w, rx[8 * j2 + 3], v0);
        float v1 = cwC.x * rx[8 * j2 + 4];
        v1 = fmaf(cwC.y, rx[8 * j2 + 5], v1);
        v1 = fmaf(cwC.z, rx[8 * j2 + 6], v1);
        v1 = fmaf(cwC.w, rx[8 * j2 + 7], v1);
        pkv[j2] = pk2(v0, v1);
      }
      *(uint4*)(sA + aslot) = make_uint4(pkv[0], pkv[1], pkv[2], pkv[3]);
    }
    // ---- prefetch chunk t+1: next tap's corner regs + 32 x-loads ----
    {
      const int tn = t < 35 ? t + 1 : 35;  // clamp: last iter reloads (unused)
      const int cqn = tn / 9;
      const int tapn = tn - cqn * 9;
      uint2 p = s_cw[(tapn << 5) + ctab];
      float4 cwN;
      cwN.x = __uint_as_float(p.x << 16);
      cwN.y = __uint_as_float(p.x & 0xffff0000u);
      cwN.z = __uint_as_float(p.y << 16);
      cwN.w = __uint_as_float(p.y & 0xffff0000u);
      ushort4 ciN = s_ci[(tapn << 5) + ctab];
      const float* xpn = xb + ((cqn << 6) + (cgs << 3)) * HWN;
#pragma unroll
      for (int s = 0; s < 8; ++s) {
        const float* xp = xpn + s * HWN;
        rx[4 * s + 0] = xp[ciN.x];
        rx[4 * s + 1] = xp[ciN.y];
        rx[4 * s + 2] = xp[ciN.z];
        rx[4 * s + 3] = xp[ciN.w];
      }
      cwC = cwN;
    }
    PIPE_BARRIER();  // sA visible; prefetch + rb loads stay in flight
    // ---- MFMA: 2 k-steps x 2 mfrag x 4 nfrag ----
    __builtin_amdgcn_s_setprio(1);
#pragma unroll
    for (int ks = 0; ks < 2; ++ks) {
      bf16x8 af[2];
#pragma unroll
      for (int mf = 0; mf < 2; ++mf) {
        int row = (mf << 4) + (lane & 15);
        int slot = ((ks << 2) + (lane >> 4)) ^ (row & 7);
        af[mf] = *(bf16x8*)(sA + (row << 7) + (slot << 4));
      }
#pragma unroll
      for (int mf = 0; mf < 2; ++mf)
#pragma unroll
        for (int nf = 0; nf < 4; ++nf)
          acc[mf][nf] = __builtin_amdgcn_mfma_f32_16x16x32_bf16(
              af[mf], rb[nf][ks], acc[mf][nf], 0, 0, 0);
    }
    __builtin_amdgcn_s_setprio(0);
    PIPE_BARRIER();  // frag reads done before next iteration's writes
  }

  // ---- BN partials (sum over this block's 32 px) + direct stores ----
#pragma unroll
  for (int nf = 0; nf < 4; ++nf) {
    float s = 0.f, q = 0.f;
#pragma unroll
    for (int mf = 0; mf < 2; ++mf)
#pragma unroll
      for (int r = 0; r < 4; ++r) {
        float v = acc[mf][nf][r];
        s += v;
        q = fmaf(v, v, q);
      }
    s += __shfl_xor(s, 16);
    q += __shfl_xor(q, 16);
    s += __shfl_xor(s, 32);
    q += __shfl_xor(q, 32);
    if (lane < 16) {
      int o = (wv << 6) + (nf << 4) + lane;
      psum[(o << 10) + bid] = s;
      psq[(o << 10) + bid] = q;
    }
  }
#pragma unroll
  for (int mf = 0; mf < 2; ++mf)
#pragma unroll
    for (int nf = 0; nf < 4; ++nf) {
      int o = (wv << 6) + (nf << 4) + (lane & 15);
      float* op = out + (((b << 8) + o) << 12) + (h << 6) + (half << 5) +
                  (mf << 4) + ((lane >> 4) << 2);
      *(float4*)op = make_float4(acc[mf][nf][0], acc[mf][nf][1],
                                 acc[mf][nf][2], acc[mf][nf][3]);
    }
}

// ---------------------------------------------------------------------------
// Kernel 3: per-channel stats -> scale/shift (1024 partials per channel).
// ---------------------------------------------------------------------------
__global__ __launch_bounds__(64) void k_stats(
    const float* __restrict__ psum, const float* __restrict__ psq,
    const float* __restrict__ gamma, const float* __restrict__ beta,
    float* __restrict__ scale, float* __restrict__ shift) {
  const int o = blockIdx.x;
  const int t = threadIdx.x;
  float s = 0.f, q = 0.f;
#pragma unroll
  for (int i = 0; i < 16; ++i) {
    s += psum[(o << 10) + t + (i << 6)];
    q += psq[(o << 10) + t + (i << 6)];
  }
#pragma unroll
  for (int off = 32; off > 0; off >>= 1) {
    s += __shfl_down(s, off, 64);
    q += __shfl_down(q, off, 64);
  }
  if (t == 0) {
    const float inv_n = 1.f / 32768.f;
    float mean = s * inv_n;
    float var = fmaf(-mean, mean, q * inv_n);
    float sc = gamma[o] * rsqrtf(var + 1e-5f);
    scale[o] = sc;
    shift[o] = fmaf(-mean, sc, beta[o]);
  }
}

// ---------------------------------------------------------------------------
// Kernel 4: in-place BN + ReLU over d_out (float4 elementwise).
// ---------------------------------------------------------------------------
__global__ __launch_bounds__(256) void k_bnrelu(
    float* __restrict__ out, const float* __restrict__ scale,
    const float* __restrict__ shift) {
  int idx = blockIdx.x * 256 + threadIdx.x;
  int o = (idx >> 10) & 255;
  float sc = scale[o], sh = shift[o];
  float4 v = ((float4*)out)[idx];
  v.x = fmaxf(fmaf(v.x, sc, sh), 0.f);
  v.y = fmaxf(fmaf(v.y, sc, sh), 0.f);
  v.z = fmaxf(fmaf(v.z, sc, sh), 0.f);
  v.w = fmaxf(fmaf(v.w, sc, sh), 0.f);
  ((float4*)out)[idx] = v;
}

extern "C" void kernel_launch(void* const* d_in, const int* in_sizes, int n_in,
                              void* d_out, int out_size, void* d_ws,
                              size_t ws_size, hipStream_t stream) {
  const float* x = (const float*)d_in[0];
  const float* ow = (const float*)d_in[1];
  const float* ob = (const float*)d_in[2];
  const float* mw = (const float*)d_in[3];
  const float* mb = (const float*)d_in[4];
  const float* wgt = (const float*)d_in[5];
  // d_in[6] = conv bias: cancels exactly in BN (out - mean(out)), skipped.
  const float* gamma = (const float*)d_in[7];
  const float* beta = (const float*)d_in[8];
  float* out = (float*)d_out;

  // workspace layout: 6.76 MiB
  float* ws = (float*)d_ws;
  float* dyb = ws;                  // 294912
  float* dxb = dyb + 294912;        // 294912
  float* mskb = dxb + 294912;       // 294912
  float* psum = mskb + 294912;      // 256*1024 = 262144
  float* psq = psum + 262144;       // 262144
  float* scale = psq + 262144;      // 256
  float* shift = scale + 256;       // 256
  unsigned short* wT = (unsigned short*)(shift + 256);  // 9*256*256 bf16

  k_wprep<<<256, 256, 0, stream>>>(wgt, wT);
  k_offmod<<<512, 512, 0, stream>>>(x, ow, ob, mw, mb, dyb, dxb, mskb);
  k_main<<<1024, 256, 0, stream>>>(x, wT, dyb, dxb, mskb, out, psum, psq);
  k_stats<<<256, 64, 0, stream>>>(psum, psq, gamma, beta, scale, shift);
  k_bnrelu<<<8192, 256, 0, stream>>>(out, scale, shift);
}

// Round 10
// 268.200 us; speedup vs baseline: 1.6155x; 1.6155x over previous
//
#include <hip/hip_runtime.h>
#include <math.h>

#define CI 256
#define CO 256
#define HWN 4096  // H*W

typedef short bf16x8 __attribute__((ext_vector_type(8)));
typedef float f32x4 __attribute__((ext_vector_type(4)));

__device__ inline unsigned pk2(float a, float b) {  // RNE pack 2 f32 -> 2 bf16
  unsigned ua = __float_as_uint(a), ub = __float_as_uint(b);
  ua += 0x7fff + ((ua >> 16) & 1);
  ub += 0x7fff + ((ub >> 16) & 1);
  return (ua >> 16) | (ub & 0xffff0000u);
}

// Raw barrier that does NOT drain vmcnt (keeps prefetch loads in flight).
#define PIPE_BARRIER()                                    \
  do {                                                    \
    __builtin_amdgcn_sched_barrier(0);                    \
    asm volatile("s_waitcnt lgkmcnt(0)" ::: "memory");    \
    __builtin_amdgcn_s_barrier();                         \
    __builtin_amdgcn_sched_barrier(0);                    \
  } while (0)

// ---------------------------------------------------------------------------
// Kernel 0a: x f32 -> bf16 (RNE), 8 elements/thread.
// ---------------------------------------------------------------------------
__global__ __launch_bounds__(256) void k_xprep(const float4* __restrict__ xf,
                                               uint4* __restrict__ xh) {
  int i = blockIdx.x * 256 + threadIdx.x;
  float4 a = xf[2 * i], b = xf[2 * i + 1];
  xh[i] = make_uint4(pk2(a.x, a.y), pk2(a.z, a.w), pk2(b.x, b.y),
                     pk2(b.z, b.w));
}

// ---------------------------------------------------------------------------
// Kernel 0b: weight pre-transpose+convert: w[o][c][tap] f32 -> wT[tap][o][c] bf16
// ---------------------------------------------------------------------------
__global__ __launch_bounds__(256) void k_wprep(const float* __restrict__ wgt,
                                               unsigned short* __restrict__ wT) {
  const int o = blockIdx.x, c = threadIdx.x;
  const float* wp = wgt + o * 2304 + c * 9;
  float v[9];
#pragma unroll
  for (int t = 0; t < 9; ++t) v[t] = wp[t];
#pragma unroll
  for (int t = 0; t < 9; ++t) {
    unsigned u = __float_as_uint(v[t]);
    u += 0x7fff + ((u >> 16) & 1);
    wT[(t << 16) + (o << 8) + c] = (unsigned short)(u >> 16);
  }
}

// ---------------------------------------------------------------------------
// Kernel 1: offset (18ch) + modulation (9ch) 3x3 conv over Ci=256. R5-exact.
// ---------------------------------------------------------------------------
__global__ __launch_bounds__(512, 4) void k_offmod(
    const float* __restrict__ x, const float* __restrict__ ow,
    const float* __restrict__ ob, const float* __restrict__ mw,
    const float* __restrict__ mb, float* __restrict__ dyb,
    float* __restrict__ dxb, float* __restrict__ mskb) {
  __shared__ float xs[1584];   // 8 ch * 3 rows * 66 cols
  __shared__ float ps[13824];  // 64 px * 27 ch * 8 groups
  const int tid = threadIdx.x;
  const int bh = blockIdx.x;
  const int b = bh >> 6, h = bh & 63;
  const int cg = __builtin_amdgcn_readfirstlane(tid >> 6);  // wave id 0..7
  const int px = tid & 63;
  float acc[27];
#pragma unroll
  for (int i = 0; i < 27; ++i) acc[i] = 0.f;
  const float* xb = x + b * (CI * HWN);
  for (int t = 0; t < 32; ++t) {
    __syncthreads();
    for (int i = tid; i < 1584; i += 512) {
      int cl = i / 198;
      int rem = i - cl * 198;
      int r = rem / 66;
      int col = rem - r * 66 - 1;
      int hh = h - 1 + r;
      float v = 0.f;
      if (hh >= 0 && hh < 64 && col >= 0 && col < 64)
        v = xb[(8 * t + cl) * HWN + hh * 64 + col];
      xs[i] = v;
    }
    __syncthreads();
    float xv[9];
#pragma unroll
    for (int r = 0; r < 3; ++r)
#pragma unroll
      for (int kx = 0; kx < 3; ++kx)
        xv[r * 3 + kx] = xs[cg * 198 + r * 66 + px + kx];
    const int c = 8 * t + cg;
    const float* owp = ow + c * 9;
    const float* mwp = mw + c * 9;
#pragma unroll
    for (int ch = 0; ch < 18; ++ch)
#pragma unroll
      for (int k = 0; k < 9; ++k)
        acc[ch] = fmaf(owp[ch * 2304 + k], xv[k], acc[ch]);
#pragma unroll
    for (int ch = 0; ch < 9; ++ch)
#pragma unroll
      for (int k = 0; k < 9; ++k)
        acc[18 + ch] = fmaf(mwp[ch * 2304 + k], xv[k], acc[18 + ch]);
  }
  __syncthreads();
#pragma unroll
  for (int ch = 0; ch < 27; ++ch) ps[(px * 27 + ch) * 8 + cg] = acc[ch];
  __syncthreads();
  for (int i = tid; i < 1728; i += 512) {
    int p2 = i / 27;
    int ch = i - p2 * 27;
    float s = 0.f;
#pragma unroll
    for (int g = 0; g < 8; ++g) s += ps[i * 8 + g];
    if (ch < 18) {
      s += ob[ch];
      int k = ch >> 1;
      int o9 = ((b * 9 + k) << 12) + (h << 6) + p2;
      if ((ch & 1) == 0) dyb[o9] = s;
      else dxb[o9] = s;
    } else {
      int k = ch - 18;
      s += mb[k];
      mskb[((b * 9 + k) << 12) + (h << 6) + p2] = 2.f / (1.f + expf(-s));
    }
  }
}

// ---------------------------------------------------------------------------
// Kernel 2 (bf16-x path): R5 structure with PAIR gathers. Since x1=x0+1, the
// two x-adjacent corners of each row live in ONE dword of bf16-x. Per sample:
// 2 scattered dword loads (vs 4 f32) with refolded weights
//   sample = a0*lo(d0)+b0*hi(d0)+a1*lo(d1)+b1*hi(d1)
// where (a,b) absorb clamp/validity: s0=x0c-xp, s1=x1c-xp, xp=clamp(x0,0,62);
// a0=(s0?0:w00)+(s1?0:w01), b0=(s0?w00:0)+(s1?w01:0); same for row1.
// Halves gather instructions AND halves cache-lines touched per load.
// ---------------------------------------------------------------------------
__global__ __launch_bounds__(512, 4) void k_main_h(
    const unsigned short* __restrict__ xh, const unsigned short* __restrict__ wT,
    const float* __restrict__ dyb, const float* __restrict__ dxb,
    const float* __restrict__ mskb, float* __restrict__ out,
    float* __restrict__ psum, float* __restrict__ psq) {
  __shared__ __align__(16) char smem[47872];
  uint2* s_cw = (uint2*)smem;                // [9][64] a0b0|a1b1 bf16, 4608 B
  ushort2* s_ci = (ushort2*)(smem + 4608);   // [9][64] pair bases, 2304 B
  char* sA = smem + 6912;                    // 64x64 bf16 = 8192 B
  char* sB = smem + 15104;                   // 256x64 bf16 = 32768 B
  float* tr = (float*)(smem + 6912);         // epilogue reuse: 128*65*4 B

  const int tid = threadIdx.x;
  const int mblk = blockIdx.x;  // b*64 + h
  const int b = mblk >> 6, h = mblk & 63;
  const int lane = tid & 63;
  const int wv = tid >> 6;

  // ---- corner table: 9 taps * 64 px, pair form ----
  for (int i = tid; i < 576; i += 512) {
    int k = i >> 6, pxi = i & 63;
    int o9 = ((b * 9 + k) << 12) + (h << 6) + pxi;
    float m = mskb[o9];
    float py = (float)(h - 1 + k / 3) + dyb[o9];
    float pxf = (float)(pxi - 1 + k % 3) + dxb[o9];
    float y0f = floorf(py), x0f = floorf(pxf);
    float wy = py - y0f, wx = pxf - x0f;
    int y0 = (int)y0f, x0 = (int)x0f;
    int y1 = y0 + 1, x1 = x0 + 1;
    float w00 = (1.f - wy) * (1.f - wx) * m;
    float w01 = (1.f - wy) * wx * m;
    float w10 = wy * (1.f - wx) * m;
    float w11 = wy * wx * m;
    bool vy0 = ((unsigned)y0 < 64u), vy1 = ((unsigned)y1 < 64u);
    bool vx0 = ((unsigned)x0 < 64u), vx1 = ((unsigned)x1 < 64u);
    if (!(vy0 && vx0)) w00 = 0.f;
    if (!(vy0 && vx1)) w01 = 0.f;
    if (!(vy1 && vx0)) w10 = 0.f;
    if (!(vy1 && vx1)) w11 = 0.f;
    int y0c = min(max(y0, 0), 63), y1c = min(max(y1, 0), 63);
    int x0c = min(max(x0, 0), 63), x1c = min(max(x1, 0), 63);
    int xp = min(max(x0, 0), 62);
    int s0 = x0c - xp, s1 = x1c - xp;  // each in {0,1}
    float a0 = (s0 ? 0.f : w00) + (s1 ? 0.f : w01);
    float b0 = (s0 ? w00 : 0.f) + (s1 ? w01 : 0.f);
    float a1 = (s0 ? 0.f : w10) + (s1 ? 0.f : w11);
    float b1 = (s0 ? w10 : 0.f) + (s1 ? w11 : 0.f);
    s_cw[i] = make_uint2(pk2(a0, b0), pk2(a1, b1));
    s_ci[i] = make_ushort2((unsigned short)(y0c * 64 + xp),
                           (unsigned short)(y1c * 64 + xp));
  }
  __syncthreads();

  f32x4 acc[4][2];
#pragma unroll
  for (int mf = 0; mf < 4; ++mf)
#pragma unroll
    for (int nf = 0; nf < 2; ++nf) acc[mf][nf] = (f32x4){0.f, 0.f, 0.f, 0.f};

  const char* xbh = (const char*)(xh + (size_t)b * (CI * HWN));
  const int aslot = (lane << 7) + ((wv ^ (lane & 7)) << 4);

  // ---- prologue: corner regs + pair-prefetch for chunk 0 (cq=0, tap=0) ----
  unsigned rxu[16];  // [s][row]: 8 samples x 2 dwords
  float4 cwC;
  {
    uint2 p = s_cw[lane];
    cwC.x = __uint_as_float(p.x << 16);
    cwC.y = __uint_as_float(p.x & 0xffff0000u);
    cwC.z = __uint_as_float(p.y << 16);
    cwC.w = __uint_as_float(p.y & 0xffff0000u);
    ushort2 ci0 = s_ci[lane];
    const char* xcn = xbh + (((wv << 3) * HWN) << 1);
#pragma unroll
    for (int s = 0; s < 8; ++s) {
      const char* xc = xcn + ((s * HWN) << 1);
      __builtin_memcpy(&rxu[2 * s + 0], xc + ((int)ci0.x << 1), 4);
      __builtin_memcpy(&rxu[2 * s + 1], xc + ((int)ci0.y << 1), 4);
    }
  }

#pragma unroll 1
  for (int t = 0; t < 36; ++t) {
    const int cq = t / 9;
    const int tap = t - cq * 9;
    // ---- pack chunk t's prefetched pairs -> sA ----
    {
      unsigned pkv[4];
#pragma unroll
      for (int j2 = 0; j2 < 4; ++j2) {
        float vv[2];
#pragma unroll
        for (int u = 0; u < 2; ++u) {
          unsigned d0 = rxu[4 * j2 + 2 * u], d1 = rxu[4 * j2 + 2 * u + 1];
          float v = cwC.x * __uint_as_float(d0 << 16);
          v = fmaf(cwC.y, __uint_as_float(d0 & 0xffff0000u), v);
          v = fmaf(cwC.z, __uint_as_float(d1 << 16), v);
          vv[u] = fmaf(cwC.w, __uint_as_float(d1 & 0xffff0000u), v);
        }
        pkv[j2] = pk2(vv[0], vv[1]);
      }
      *(uint4*)(sA + aslot) = make_uint4(pkv[0], pkv[1], pkv[2], pkv[3]);
    }
    // ---- stage B: coalesced copy wT[tap][0..255][cq*64..+64] (R5-exact) ----
    {
      const unsigned short* wp = wT + (tap << 16) + (cq << 6);
#pragma unroll
      for (int r = 0; r < 4; ++r) {
        int idx = (r << 9) + tid;  // 0..2047
        int o = idx >> 3, seg = idx & 7;
        uint4 v = *(const uint4*)(wp + (o << 8) + (seg << 3));
        int slot = seg ^ (o & 7);
        *(uint4*)(sB + (o << 7) + (slot << 4)) = v;
      }
    }
    // ---- prefetch chunk t+1: next tap's corner regs + 16 pair-loads ----
    {
      const int tn = t < 35 ? t + 1 : 35;  // clamp: last iter reloads (unused)
      const int cqn = tn / 9;
      const int tapn = tn - cqn * 9;
      uint2 p = s_cw[(tapn << 6) + lane];
      float4 cwN;
      cwN.x = __uint_as_float(p.x << 16);
      cwN.y = __uint_as_float(p.x & 0xffff0000u);
      cwN.z = __uint_as_float(p.y << 16);
      cwN.w = __uint_as_float(p.y & 0xffff0000u);
      ushort2 ciN = s_ci[(tapn << 6) + lane];
      const char* xcn = xbh + ((((cqn << 3) + wv) << 3) * HWN << 1);
#pragma unroll
      for (int s = 0; s < 8; ++s) {
        const char* xc = xcn + ((s * HWN) << 1);
        __builtin_memcpy(&rxu[2 * s + 0], xc + ((int)ciN.x << 1), 4);
        __builtin_memcpy(&rxu[2 * s + 1], xc + ((int)ciN.y << 1), 4);
      }
      cwC = cwN;
    }
    PIPE_BARRIER();  // sA/sB visible; prefetch loads stay in flight
    // ---- MFMA: 2 k-steps x 4 mfrag x 2 nfrag (R5-exact) ----
#pragma unroll
    for (int ks = 0; ks < 2; ++ks) {
      bf16x8 af[4], bfr[2];
#pragma unroll
      for (int mf = 0; mf < 4; ++mf) {
        int row = (mf << 4) + (lane & 15);
        int slot = ((ks << 2) + (lane >> 4)) ^ (row & 7);
        af[mf] = *(bf16x8*)(sA + (row << 7) + (slot << 4));
      }
#pragma unroll
      for (int nf = 0; nf < 2; ++nf) {
        int row = (wv << 5) + (nf << 4) + (lane & 15);
        int slot = ((ks << 2) + (lane >> 4)) ^ (row & 7);
        bfr[nf] = *(bf16x8*)(sB + (row << 7) + (slot << 4));
      }
#pragma unroll
      for (int mf = 0; mf < 4; ++mf)
#pragma unroll
        for (int nf = 0; nf < 2; ++nf)
          acc[mf][nf] = __builtin_amdgcn_mfma_f32_16x16x32_bf16(
              af[mf], bfr[nf], acc[mf][nf], 0, 0, 0);
    }
    PIPE_BARRIER();  // frag reads done before next iteration's writes
  }

  // ---- BN partial stats from registers (R5-exact) ----
#pragma unroll
  for (int nf = 0; nf < 2; ++nf) {
    float s = 0.f, q = 0.f;
#pragma unroll
    for (int mf = 0; mf < 4; ++mf)
#pragma unroll
      for (int r = 0; r < 4; ++r) {
        float v = acc[mf][nf][r];
        s += v;
        q = fmaf(v, v, q);
      }
    s += __shfl_down(s, 32);
    q += __shfl_down(q, 32);
    s += __shfl_down(s, 16);
    q += __shfl_down(q, 16);
    if (lane < 16) {
      int o = (wv << 5) + (nf << 4) + lane;
      psum[(o << 9) + mblk] = s;
      psq[(o << 9) + mblk] = q;
    }
  }

  // ---- store via LDS transpose, 2 passes of 128 o-rows (R5-exact) ----
  __syncthreads();
  for (int p = 0; p < 2; ++p) {
    if ((wv >> 2) == p) {
#pragma unroll
      for (int mf = 0; mf < 4; ++mf)
#pragma unroll
        for (int nf = 0; nf < 2; ++nf) {
          int ro = ((wv & 3) << 5) + (nf << 4) + (lane & 15);
#pragma unroll
          for (int r = 0; r < 4; ++r)
            tr[ro * 65 + (mf << 4) + ((lane >> 4) << 2) + r] = acc[mf][nf][r];
        }
    }
    __syncthreads();
#pragma unroll
    for (int it = 0; it < 4; ++it) {
      int idx = tid + (it << 9);
      int ro = idx >> 4, qd = idx & 15;
      float4 v = make_float4(tr[ro * 65 + qd * 4], tr[ro * 65 + qd * 4 + 1],
                             tr[ro * 65 + qd * 4 + 2], tr[ro * 65 + qd * 4 + 3]);
      *(float4*)(out + (((b << 8) + (p << 7) + ro) << 12) + (h << 6) +
                 (qd << 2)) = v;
    }
    __syncthreads();
  }
}

// ---------------------------------------------------------------------------
// Kernel 2 fallback (f32 x): R5-exact k_main, used when ws_size is too small
// for the bf16 x copy.
// ---------------------------------------------------------------------------
__global__ __launch_bounds__(512, 4) void k_main_f32(
    const float* __restrict__ x, const unsigned short* __restrict__ wT,
    const float* __restrict__ dyb, const float* __restrict__ dxb,
    const float* __restrict__ mskb, float* __restrict__ out,
    float* __restrict__ psum, float* __restrict__ psq) {
  __shared__ __align__(16) char smem[50176];
  uint2* s_cw = (uint2*)smem;
  ushort4* s_ci = (ushort4*)(smem + 4608);
  char* sA = smem + 9216;
  char* sB = smem + 17408;
  float* tr = (float*)(smem + 9216);

  const int tid = threadIdx.x;
  const int mblk = blockIdx.x;
  const int b = mblk >> 6, h = mblk & 63;
  const int lane = tid & 63;
  const int wv = tid >> 6;

  for (int i = tid; i < 576; i += 512) {
    int k = i >> 6, pxi = i & 63;
    int o9 = ((b * 9 + k) << 12) + (h << 6) + pxi;
    float m = mskb[o9];
    float py = (float)(h - 1 + k / 3) + dyb[o9];
    float pxf = (float)(pxi - 1 + k % 3) + dxb[o9];
    float y0f = floorf(py), x0f = floorf(pxf);
    float wy = py - y0f, wx = pxf - x0f;
    int y0 = (int)y0f, x0 = (int)x0f;
    int y1 = y0 + 1, x1 = x0 + 1;
    float w00 = (1.f - wy) * (1.f - wx) * m;
    float w01 = (1.f - wy) * wx * m;
    float w10 = wy * (1.f - wx) * m;
    float w11 = wy * wx * m;
    bool vy0 = ((unsigned)y0 < 64u), vy1 = ((unsigned)y1 < 64u);
    bool vx0 = ((unsigned)x0 < 64u), vx1 = ((unsigned)x1 < 64u);
    if (!(vy0 && vx0)) w00 = 0.f;
    if (!(vy0 && vx1)) w01 = 0.f;
    if (!(vy1 && vx0)) w10 = 0.f;
    if (!(vy1 && vx1)) w11 = 0.f;
    int y0c = min(max(y0, 0), 63), y1c = min(max(y1, 0), 63);
    int x0c = min(max(x0, 0), 63), x1c = min(max(x1, 0), 63);
    s_cw[i] = make_uint2(pk2(w00, w01), pk2(w10, w11));
    s_ci[i] = make_ushort4((unsigned short)(y0c * 64 + x0c),
                           (unsigned short)(y0c * 64 + x1c),
                           (unsigned short)(y1c * 64 + x0c),
                           (unsigned short)(y1c * 64 + x1c));
  }
  __syncthreads();

  f32x4 acc[4][2];
#pragma unroll
  for (int mf = 0; mf < 4; ++mf)
#pragma unroll
    for (int nf = 0; nf < 2; ++nf) acc[mf][nf] = (f32x4){0.f, 0.f, 0.f, 0.f};

  const float* xb = x + b * (CI * HWN);
  const int aslot = (lane << 7) + ((wv ^ (lane & 7)) << 4);

  float rx[32];
  float4 cwC;
  {
    uint2 p = s_cw[lane];
    cwC.x = __uint_as_float(p.x << 16);
    cwC.y = __uint_as_float(p.x & 0xffff0000u);
    cwC.z = __uint_as_float(p.y << 16);
    cwC.w = __uint_as_float(p.y & 0xffff0000u);
    ushort4 ci0 = s_ci[lane];
    const float* xpn = xb + (wv << 3) * HWN;
#pragma unroll
    for (int s = 0; s < 8; ++s) {
      const float* xp = xpn + s * HWN;
      rx[4 * s + 0] = xp[ci0.x];
      rx[4 * s + 1] = xp[ci0.y];
      rx[4 * s + 2] = xp[ci0.z];
      rx[4 * s + 3] = xp[ci0.w];
    }
  }

#pragma unroll 1
  for (int t = 0; t < 36; ++t) {
    const int cq = t / 9;
    const int tap = t - cq * 9;
    {
      unsigned pkv[4];
#pragma unroll
      for (int j2 = 0; j2 < 4; ++j2) {
        float v0 = cwC.x * rx[8 * j2 + 0];
        v0 = fmaf(cwC.y, rx[8 * j2 + 1], v0);
        v0 = fmaf(cwC.z, rx[8 * j2 + 2], v0);
        v0 = fmaf(cwC.w, rx[8 * j2 + 3], v0);
        float v1 = cwC.x * rx[8 * j2 + 4];
        v1 = fmaf(cwC.y, rx[8 * j2 + 5], v1);
        v1 = fmaf(cwC.z, rx[8 * j2 + 6], v1);
        v1 = fmaf(cwC.w, rx[8 * j2 + 7], v1);
        pkv[j2] = pk2(v0, v1);
      }
      *(uint4*)(sA + aslot) = make_uint4(pkv[0], pkv[1], pkv[2], pkv[3]);
    }
    {
      const unsigned short* wp = wT + (tap << 16) + (cq << 6);
#pragma unroll
      for (int r = 0; r < 4; ++r) {
        int idx = (r << 9) + tid;
        int o = idx >> 3, seg = idx & 7;
        uint4 v = *(const uint4*)(wp + (o << 8) + (seg << 3));
        int slot = seg ^ (o & 7);
        *(uint4*)(sB + (o << 7) + (slot << 4)) = v;
      }
    }
    {
      const int tn = t < 35 ? t + 1 : 35;
      const int cqn = tn / 9;
      const int tapn = tn - cqn * 9;
      uint2 p = s_cw[(tapn << 6) + lane];
      float4 cwN;
      cwN.x = __uint_as_float(p.x << 16);
      cwN.y = __uint_as_float(p.x & 0xffff0000u);
      cwN.z = __uint_as_float(p.y << 16);
      cwN.w = __uint_as_float(p.y & 0xffff0000u);
      ushort4 ciN = s_ci[(tapn << 6) + lane];
      const float* xpn = xb + (((cqn << 3) + wv) << 3) * HWN;
#pragma unroll
      for (int s = 0; s < 8; ++s) {
        const float* xp = xpn + s * HWN;
        rx[4 * s + 0] = xp[ciN.x];
        rx[4 * s + 1] = xp[ciN.y];
        rx[4 * s + 2] = xp[ciN.z];
        rx[4 * s + 3] = xp[ciN.w];
      }
      cwC = cwN;
    }
    PIPE_BARRIER();
#pragma unroll
    for (int ks = 0; ks < 2; ++ks) {
      bf16x8 af[4], bfr[2];
#pragma unroll
      for (int mf = 0; mf < 4; ++mf) {
        int row = (mf << 4) + (lane & 15);
        int slot = ((ks << 2) + (lane >> 4)) ^ (row & 7);
        af[mf] = *(bf16x8*)(sA + (row << 7) + (slot << 4));
      }
#pragma unroll
      for (int nf = 0; nf < 2; ++nf) {
        int row = (wv << 5) + (nf << 4) + (lane & 15);
        int slot = ((ks << 2) + (lane >> 4)) ^ (row & 7);
        bfr[nf] = *(bf16x8*)(sB + (row << 7) + (slot << 4));
      }
#pragma unroll
      for (int mf = 0; mf < 4; ++mf)
#pragma unroll
        for (int nf = 0; nf < 2; ++nf)
          acc[mf][nf] = __builtin_amdgcn_mfma_f32_16x16x32_bf16(
              af[mf], bfr[nf], acc[mf][nf], 0, 0, 0);
    }
    PIPE_BARRIER();
  }

#pragma unroll
  for (int nf = 0; nf < 2; ++nf) {
    float s = 0.f, q = 0.f;
#pragma unroll
    for (int mf = 0; mf < 4; ++mf)
#pragma unroll
      for (int r = 0; r < 4; ++r) {
        float v = acc[mf][nf][r];
        s += v;
        q = fmaf(v, v, q);
      }
    s += __shfl_down(s, 32);
    q += __shfl_down(q, 32);
    s += __shfl_down(s, 16);
    q += __shfl_down(q, 16);
    if (lane < 16) {
      int o = (wv << 5) + (nf << 4) + lane;
      psum[(o << 9) + mblk] = s;
      psq[(o << 9) + mblk] = q;
    }
  }

  __syncthreads();
  for (int p = 0; p < 2; ++p) {
    if ((wv >> 2) == p) {
#pragma unroll
      for (int mf = 0; mf < 4; ++mf)
#pragma unroll
        for (int nf = 0; nf < 2; ++nf) {
          int ro = ((wv & 3) << 5) + (nf << 4) + (lane & 15);
#pragma unroll
          for (int r = 0; r < 4; ++r)
            tr[ro * 65 + (mf << 4) + ((lane >> 4) << 2) + r] = acc[mf][nf][r];
        }
    }
    __syncthreads();
#pragma unroll
    for (int it = 0; it < 4; ++it) {
      int idx = tid + (it << 9);
      int ro = idx >> 4, qd = idx & 15;
      float4 v = make_float4(tr[ro * 65 + qd * 4], tr[ro * 65 + qd * 4 + 1],
                             tr[ro * 65 + qd * 4 + 2], tr[ro * 65 + qd * 4 + 3]);
      *(float4*)(out + (((b << 8) + (p << 7) + ro) << 12) + (h << 6) +
                 (qd << 2)) = v;
    }
    __syncthreads();
  }
}

// ---------------------------------------------------------------------------
// Kernel 3: per-channel stats -> scale/shift (512 partials per channel).
// ---------------------------------------------------------------------------
__global__ __launch_bounds__(64) void k_stats(
    const float* __restrict__ psum, const float* __restrict__ psq,
    const float* __restrict__ gamma, const float* __restrict__ beta,
    float* __restrict__ scale, float* __restrict__ shift) {
  const int o = blockIdx.x;
  const int t = threadIdx.x;
  float s = 0.f, q = 0.f;
#pragma unroll
  for (int i = 0; i < 8; ++i) {
    s += psum[(o << 9) + t + (i << 6)];
    q += psq[(o << 9) + t + (i << 6)];
  }
#pragma unroll
  for (int off = 32; off > 0; off >>= 1) {
    s += __shfl_down(s, off, 64);
    q += __shfl_down(q, off, 64);
  }
  if (t == 0) {
    const float inv_n = 1.f / 32768.f;
    float mean = s * inv_n;
    float var = fmaf(-mean, mean, q * inv_n);
    float sc = gamma[o] * rsqrtf(var + 1e-5f);
    scale[o] = sc;
    shift[o] = fmaf(-mean, sc, beta[o]);
  }
}

// ---------------------------------------------------------------------------
// Kernel 4: in-place BN + ReLU over d_out (float4 elementwise).
// ---------------------------------------------------------------------------
__global__ __launch_bounds__(256) void k_bnrelu(
    float* __restrict__ out, const float* __restrict__ scale,
    const float* __restrict__ shift) {
  int idx = blockIdx.x * 256 + threadIdx.x;
  int o = (idx >> 10) & 255;
  float sc = scale[o], sh = shift[o];
  float4 v = ((float4*)out)[idx];
  v.x = fmaxf(fmaf(v.x, sc, sh), 0.f);
  v.y = fmaxf(fmaf(v.y, sc, sh), 0.f);
  v.z = fmaxf(fmaf(v.z, sc, sh), 0.f);
  v.w = fmaxf(fmaf(v.w, sc, sh), 0.f);
  ((float4*)out)[idx] = v;
}

extern "C" void kernel_launch(void* const* d_in, const int* in_sizes, int n_in,
                              void* d_out, int out_size, void* d_ws,
                              size_t ws_size, hipStream_t stream) {
  const float* x = (const float*)d_in[0];
  const float* ow = (const float*)d_in[1];
  const float* ob = (const float*)d_in[2];
  const float* mw = (const float*)d_in[3];
  const float* mb = (const float*)d_in[4];
  const float* wgt = (const float*)d_in[5];
  // d_in[6] = conv bias: cancels exactly in BN (out - mean(out)), skipped.
  const float* gamma = (const float*)d_in[7];
  const float* beta = (const float*)d_in[8];
  float* out = (float*)d_out;

  // workspace: proven R5 layout (5.50 MiB) + optional bf16-x copy at tail.
  float* ws = (float*)d_ws;
  float* dyb = ws;                  // 294912
  float* dxb = dyb + 294912;        // 294912
  float* mskb = dxb + 294912;       // 294912
  float* psum = mskb + 294912;      // 256*512 = 131072
  float* psq = psum + 131072;       // 131072
  float* scale = psq + 131072;      // 256
  float* shift = scale + 256;       // 256
  unsigned short* wT = (unsigned short*)(shift + 256);  // 9*256*256 bf16
  unsigned short* xhp = wT + 589824;                    // 8.39M bf16 (opt.)
  const size_t WS_NEED =
      (size_t)(294912 * 3 + 131072 * 2 + 512) * 4 + 589824 * 2 + 8388608 * 2;

  k_wprep<<<256, 256, 0, stream>>>(wgt, wT);
  k_offmod<<<512, 512, 0, stream>>>(x, ow, ob, mw, mb, dyb, dxb, mskb);
  if (ws_size >= WS_NEED) {
    k_xprep<<<4096, 256, 0, stream>>>((const float4*)x, (uint4*)xhp);
    k_main_h<<<512, 512, 0, stream>>>(xhp, wT, dyb, dxb, mskb, out, psum, psq);
  } else {
    k_main_f32<<<512, 512, 0, stream>>>(x, wT, dyb, dxb, mskb, out, psum, psq);
  }
  k_stats<<<256, 64, 0, stream>>>(psum, psq, gamma, beta, scale, shift);
  k_bnrelu<<<8192, 256, 0, stream>>>(out, scale, shift);
}

// Round 11
// 259.411 us; speedup vs baseline: 1.6703x; 1.0339x over previous
//
#include <hip/hip_runtime.h>
#include <math.h>

#define CI 256
#define CO 256
#define HWN 4096  // H*W

typedef short bf16x8 __attribute__((ext_vector_type(8)));
typedef float f32x4 __attribute__((ext_vector_type(4)));

__device__ inline unsigned pk2(float a, float b) {  // RNE pack 2 f32 -> 2 bf16
  unsigned ua = __float_as_uint(a), ub = __float_as_uint(b);
  ua += 0x7fff + ((ua >> 16) & 1);
  ub += 0x7fff + ((ub >> 16) & 1);
  return (ua >> 16) | (ub & 0xffff0000u);
}

// Raw barrier that does NOT drain vmcnt (keeps prefetch loads in flight).
#define PIPE_BARRIER()                                    \
  do {                                                    \
    __builtin_amdgcn_sched_barrier(0);                    \
    asm volatile("s_waitcnt lgkmcnt(0)" ::: "memory");    \
    __builtin_amdgcn_s_barrier();                         \
    __builtin_amdgcn_sched_barrier(0);                    \
  } while (0)

// ---------------------------------------------------------------------------
// Kernel 0a: x f32 -> bf16 (RNE), 8 elements/thread.
// ---------------------------------------------------------------------------
__global__ __launch_bounds__(256) void k_xprep(const float4* __restrict__ xf,
                                               uint4* __restrict__ xh) {
  int i = blockIdx.x * 256 + threadIdx.x;
  float4 a = xf[2 * i], b = xf[2 * i + 1];
  xh[i] = make_uint4(pk2(a.x, a.y), pk2(a.z, a.w), pk2(b.x, b.y),
                     pk2(b.z, b.w));
}

// ---------------------------------------------------------------------------
// Kernel 0b: weight pre-transpose+convert: w[o][c][tap] f32 -> wT[tap][o][c] bf16
// ---------------------------------------------------------------------------
__global__ __launch_bounds__(256) void k_wprep(const float* __restrict__ wgt,
                                               unsigned short* __restrict__ wT) {
  const int o = blockIdx.x, c = threadIdx.x;
  const float* wp = wgt + o * 2304 + c * 9;
  float v[9];
#pragma unroll
  for (int t = 0; t < 9; ++t) v[t] = wp[t];
#pragma unroll
  for (int t = 0; t < 9; ++t) {
    unsigned u = __float_as_uint(v[t]);
    u += 0x7fff + ((u >> 16) & 1);
    wT[(t << 16) + (o << 8) + c] = (unsigned short)(u >> 16);
  }
}

// ---------------------------------------------------------------------------
// Kernel 1: offset (18ch) + modulation (9ch) 3x3 conv over Ci=256.
// REWRITTEN barrier-free: wave cg owns channels [cg*32, cg*32+32); per
// channel: 3 direct column loads (rows h-1,h,h+1, row-clamped + zero-select),
// neighbors via __shfl_up/down (edge lanes zeroed), 243 FMAs with
// wave-uniform scalar weight loads. No LDS x-staging, no per-iter barriers;
// ONE final barrier for the 8-group LDS reduce. b = bid&7 pins each image's
// row-blocks to one XCD so h-adjacent blocks share the x slab in L2.
// ---------------------------------------------------------------------------
__global__ __launch_bounds__(512, 4) void k_offmod(
    const float* __restrict__ x, const float* __restrict__ ow,
    const float* __restrict__ ob, const float* __restrict__ mw,
    const float* __restrict__ mb, float* __restrict__ dyb,
    float* __restrict__ dxb, float* __restrict__ mskb) {
  __shared__ float ps[13824];  // 64 px * 27 ch * 8 groups
  const int tid = threadIdx.x;
  const int bid = blockIdx.x;
  const int b = bid & 7;   // XCD-pinned image
  const int h = bid >> 3;  // 0..63
  const int cg = __builtin_amdgcn_readfirstlane(tid >> 6);  // wave id 0..7
  const int px = tid & 63;
  float acc[27];
#pragma unroll
  for (int i = 0; i < 27; ++i) acc[i] = 0.f;

  const float* xb = x + b * (CI * HWN);
  const int h0c = max(h - 1, 0), h2c = min(h + 1, 63);
  const bool v0 = h > 0, v2 = h < 63;
  const bool e0 = (px == 0), e63 = (px == 63);
  const float* xw = xb + (cg << 5) * HWN;  // wave's channel base

#pragma unroll 1
  for (int i = 0; i < 32; ++i) {
    const float* xc = xw + i * HWN;
    float c0 = xc[h0c * 64 + px];
    float c1 = xc[h * 64 + px];
    float c2 = xc[h2c * 64 + px];
    c0 = v0 ? c0 : 0.f;
    c2 = v2 ? c2 : 0.f;
    float l0 = __shfl_up(c0, 1), l1 = __shfl_up(c1, 1), l2 = __shfl_up(c2, 1);
    float r0 = __shfl_down(c0, 1), r1 = __shfl_down(c1, 1),
          r2 = __shfl_down(c2, 1);
    l0 = e0 ? 0.f : l0;
    l1 = e0 ? 0.f : l1;
    l2 = e0 ? 0.f : l2;
    r0 = e63 ? 0.f : r0;
    r1 = e63 ? 0.f : r1;
    r2 = e63 ? 0.f : r2;
    float xv[9] = {l0, c0, r0, l1, c1, r1, l2, c2, r2};
    const int c = (cg << 5) + i;
    const float* owp = ow + c * 9;
    const float* mwp = mw + c * 9;
#pragma unroll
    for (int ch = 0; ch < 18; ++ch)
#pragma unroll
      for (int k = 0; k < 9; ++k)
        acc[ch] = fmaf(owp[ch * 2304 + k], xv[k], acc[ch]);
#pragma unroll
    for (int ch = 0; ch < 9; ++ch)
#pragma unroll
      for (int k = 0; k < 9; ++k)
        acc[18 + ch] = fmaf(mwp[ch * 2304 + k], xv[k], acc[18 + ch]);
  }

#pragma unroll
  for (int ch = 0; ch < 27; ++ch) ps[(px * 27 + ch) * 8 + cg] = acc[ch];
  __syncthreads();
  for (int i = tid; i < 1728; i += 512) {
    int p2 = i / 27;
    int ch = i - p2 * 27;
    float s = 0.f;
#pragma unroll
    for (int g = 0; g < 8; ++g) s += ps[i * 8 + g];
    if (ch < 18) {
      s += ob[ch];
      int k = ch >> 1;
      int o9 = ((b * 9 + k) << 12) + (h << 6) + p2;
      if ((ch & 1) == 0) dyb[o9] = s;
      else dxb[o9] = s;
    } else {
      int k = ch - 18;
      s += mb[k];
      mskb[((b * 9 + k) << 12) + (h << 6) + p2] = 2.f / (1.f + expf(-s));
    }
  }
}

// ---------------------------------------------------------------------------
// Kernel 2 (bf16-x path): R10-exact. PAIR gathers: since x1=x0+1, the two
// x-adjacent corners of each row live in ONE dword of bf16-x.
// ---------------------------------------------------------------------------
__global__ __launch_bounds__(512, 4) void k_main_h(
    const unsigned short* __restrict__ xh, const unsigned short* __restrict__ wT,
    const float* __restrict__ dyb, const float* __restrict__ dxb,
    const float* __restrict__ mskb, float* __restrict__ out,
    float* __restrict__ psum, float* __restrict__ psq) {
  __shared__ __align__(16) char smem[47872];
  uint2* s_cw = (uint2*)smem;                // [9][64] a0b0|a1b1 bf16, 4608 B
  ushort2* s_ci = (ushort2*)(smem + 4608);   // [9][64] pair bases, 2304 B
  char* sA = smem + 6912;                    // 64x64 bf16 = 8192 B
  char* sB = smem + 15104;                   // 256x64 bf16 = 32768 B
  float* tr = (float*)(smem + 6912);         // epilogue reuse: 128*65*4 B

  const int tid = threadIdx.x;
  const int mblk = blockIdx.x;  // b*64 + h
  const int b = mblk >> 6, h = mblk & 63;
  const int lane = tid & 63;
  const int wv = tid >> 6;

  // ---- corner table: 9 taps * 64 px, pair form ----
  for (int i = tid; i < 576; i += 512) {
    int k = i >> 6, pxi = i & 63;
    int o9 = ((b * 9 + k) << 12) + (h << 6) + pxi;
    float m = mskb[o9];
    float py = (float)(h - 1 + k / 3) + dyb[o9];
    float pxf = (float)(pxi - 1 + k % 3) + dxb[o9];
    float y0f = floorf(py), x0f = floorf(pxf);
    float wy = py - y0f, wx = pxf - x0f;
    int y0 = (int)y0f, x0 = (int)x0f;
    int y1 = y0 + 1, x1 = x0 + 1;
    float w00 = (1.f - wy) * (1.f - wx) * m;
    float w01 = (1.f - wy) * wx * m;
    float w10 = wy * (1.f - wx) * m;
    float w11 = wy * wx * m;
    bool vy0 = ((unsigned)y0 < 64u), vy1 = ((unsigned)y1 < 64u);
    bool vx0 = ((unsigned)x0 < 64u), vx1 = ((unsigned)x1 < 64u);
    if (!(vy0 && vx0)) w00 = 0.f;
    if (!(vy0 && vx1)) w01 = 0.f;
    if (!(vy1 && vx0)) w10 = 0.f;
    if (!(vy1 && vx1)) w11 = 0.f;
    int y0c = min(max(y0, 0), 63), y1c = min(max(y1, 0), 63);
    int x0c = min(max(x0, 0), 63), x1c = min(max(x1, 0), 63);
    int xp = min(max(x0, 0), 62);
    int s0 = x0c - xp, s1 = x1c - xp;  // each in {0,1}
    float a0 = (s0 ? 0.f : w00) + (s1 ? 0.f : w01);
    float b0 = (s0 ? w00 : 0.f) + (s1 ? w01 : 0.f);
    float a1 = (s0 ? 0.f : w10) + (s1 ? 0.f : w11);
    float b1 = (s0 ? w10 : 0.f) + (s1 ? w11 : 0.f);
    s_cw[i] = make_uint2(pk2(a0, b0), pk2(a1, b1));
    s_ci[i] = make_ushort2((unsigned short)(y0c * 64 + xp),
                           (unsigned short)(y1c * 64 + xp));
  }
  __syncthreads();

  f32x4 acc[4][2];
#pragma unroll
  for (int mf = 0; mf < 4; ++mf)
#pragma unroll
    for (int nf = 0; nf < 2; ++nf) acc[mf][nf] = (f32x4){0.f, 0.f, 0.f, 0.f};

  const char* xbh = (const char*)(xh + (size_t)b * (CI * HWN));
  const int aslot = (lane << 7) + ((wv ^ (lane & 7)) << 4);

  // ---- prologue: corner regs + pair-prefetch for chunk 0 (cq=0, tap=0) ----
  unsigned rxu[16];  // [s][row]: 8 samples x 2 dwords
  float4 cwC;
  {
    uint2 p = s_cw[lane];
    cwC.x = __uint_as_float(p.x << 16);
    cwC.y = __uint_as_float(p.x & 0xffff0000u);
    cwC.z = __uint_as_float(p.y << 16);
    cwC.w = __uint_as_float(p.y & 0xffff0000u);
    ushort2 ci0 = s_ci[lane];
    const char* xcn = xbh + (((wv << 3) * HWN) << 1);
#pragma unroll
    for (int s = 0; s < 8; ++s) {
      const char* xc = xcn + ((s * HWN) << 1);
      __builtin_memcpy(&rxu[2 * s + 0], xc + ((int)ci0.x << 1), 4);
      __builtin_memcpy(&rxu[2 * s + 1], xc + ((int)ci0.y << 1), 4);
    }
  }

#pragma unroll 1
  for (int t = 0; t < 36; ++t) {
    const int cq = t / 9;
    const int tap = t - cq * 9;
    // ---- pack chunk t's prefetched pairs -> sA ----
    {
      unsigned pkv[4];
#pragma unroll
      for (int j2 = 0; j2 < 4; ++j2) {
        float vv[2];
#pragma unroll
        for (int u = 0; u < 2; ++u) {
          unsigned d0 = rxu[4 * j2 + 2 * u], d1 = rxu[4 * j2 + 2 * u + 1];
          float v = cwC.x * __uint_as_float(d0 << 16);
          v = fmaf(cwC.y, __uint_as_float(d0 & 0xffff0000u), v);
          v = fmaf(cwC.z, __uint_as_float(d1 << 16), v);
          vv[u] = fmaf(cwC.w, __uint_as_float(d1 & 0xffff0000u), v);
        }
        pkv[j2] = pk2(vv[0], vv[1]);
      }
      *(uint4*)(sA + aslot) = make_uint4(pkv[0], pkv[1], pkv[2], pkv[3]);
    }
    // ---- stage B: coalesced copy wT[tap][0..255][cq*64..+64] ----
    {
      const unsigned short* wp = wT + (tap << 16) + (cq << 6);
#pragma unroll
      for (int r = 0; r < 4; ++r) {
        int idx = (r << 9) + tid;  // 0..2047
        int o = idx >> 3, seg = idx & 7;
        uint4 v = *(const uint4*)(wp + (o << 8) + (seg << 3));
        int slot = seg ^ (o & 7);
        *(uint4*)(sB + (o << 7) + (slot << 4)) = v;
      }
    }
    // ---- prefetch chunk t+1: next tap's corner regs + 16 pair-loads ----
    {
      const int tn = t < 35 ? t + 1 : 35;  // clamp: last iter reloads (unused)
      const int cqn = tn / 9;
      const int tapn = tn - cqn * 9;
      uint2 p = s_cw[(tapn << 6) + lane];
      float4 cwN;
      cwN.x = __uint_as_float(p.x << 16);
      cwN.y = __uint_as_float(p.x & 0xffff0000u);
      cwN.z = __uint_as_float(p.y << 16);
      cwN.w = __uint_as_float(p.y & 0xffff0000u);
      ushort2 ciN = s_ci[(tapn << 6) + lane];
      const char* xcn = xbh + ((((cqn << 3) + wv) << 3) * HWN << 1);
#pragma unroll
      for (int s = 0; s < 8; ++s) {
        const char* xc = xcn + ((s * HWN) << 1);
        __builtin_memcpy(&rxu[2 * s + 0], xc + ((int)ciN.x << 1), 4);
        __builtin_memcpy(&rxu[2 * s + 1], xc + ((int)ciN.y << 1), 4);
      }
      cwC = cwN;
    }
    PIPE_BARRIER();  // sA/sB visible; prefetch loads stay in flight
    // ---- MFMA: 2 k-steps x 4 mfrag x 2 nfrag ----
#pragma unroll
    for (int ks = 0; ks < 2; ++ks) {
      bf16x8 af[4], bfr[2];
#pragma unroll
      for (int mf = 0; mf < 4; ++mf) {
        int row = (mf << 4) + (lane & 15);
        int slot = ((ks << 2) + (lane >> 4)) ^ (row & 7);
        af[mf] = *(bf16x8*)(sA + (row << 7) + (slot << 4));
      }
#pragma unroll
      for (int nf = 0; nf < 2; ++nf) {
        int row = (wv << 5) + (nf << 4) + (lane & 15);
        int slot = ((ks << 2) + (lane >> 4)) ^ (row & 7);
        bfr[nf] = *(bf16x8*)(sB + (row << 7) + (slot << 4));
      }
#pragma unroll
      for (int mf = 0; mf < 4; ++mf)
#pragma unroll
        for (int nf = 0; nf < 2; ++nf)
          acc[mf][nf] = __builtin_amdgcn_mfma_f32_16x16x32_bf16(
              af[mf], bfr[nf], acc[mf][nf], 0, 0, 0);
    }
    PIPE_BARRIER();  // frag reads done before next iteration's writes
  }

  // ---- BN partial stats from registers ----
#pragma unroll
  for (int nf = 0; nf < 2; ++nf) {
    float s = 0.f, q = 0.f;
#pragma unroll
    for (int mf = 0; mf < 4; ++mf)
#pragma unroll
      for (int r = 0; r < 4; ++r) {
        float v = acc[mf][nf][r];
        s += v;
        q = fmaf(v, v, q);
      }
    s += __shfl_down(s, 32);
    q += __shfl_down(q, 32);
    s += __shfl_down(s, 16);
    q += __shfl_down(q, 16);
    if (lane < 16) {
      int o = (wv << 5) + (nf << 4) + lane;
      psum[(o << 9) + mblk] = s;
      psq[(o << 9) + mblk] = q;
    }
  }

  // ---- store via LDS transpose, 2 passes of 128 o-rows ----
  __syncthreads();
  for (int p = 0; p < 2; ++p) {
    if ((wv >> 2) == p) {
#pragma unroll
      for (int mf = 0; mf < 4; ++mf)
#pragma unroll
        for (int nf = 0; nf < 2; ++nf) {
          int ro = ((wv & 3) << 5) + (nf << 4) + (lane & 15);
#pragma unroll
          for (int r = 0; r < 4; ++r)
            tr[ro * 65 + (mf << 4) + ((lane >> 4) << 2) + r] = acc[mf][nf][r];
        }
    }
    __syncthreads();
#pragma unroll
    for (int it = 0; it < 4; ++it) {
      int idx = tid + (it << 9);
      int ro = idx >> 4, qd = idx & 15;
      float4 v = make_float4(tr[ro * 65 + qd * 4], tr[ro * 65 + qd * 4 + 1],
                             tr[ro * 65 + qd * 4 + 2], tr[ro * 65 + qd * 4 + 3]);
      *(float4*)(out + (((b << 8) + (p << 7) + ro) << 12) + (h << 6) +
                 (qd << 2)) = v;
    }
    __syncthreads();
  }
}

// ---------------------------------------------------------------------------
// Kernel 2 fallback (f32 x): R5-exact k_main, used when ws_size is too small
// for the bf16 x copy.
// ---------------------------------------------------------------------------
__global__ __launch_bounds__(512, 4) void k_main_f32(
    const float* __restrict__ x, const unsigned short* __restrict__ wT,
    const float* __restrict__ dyb, const float* __restrict__ dxb,
    const float* __restrict__ mskb, float* __restrict__ out,
    float* __restrict__ psum, float* __restrict__ psq) {
  __shared__ __align__(16) char smem[50176];
  uint2* s_cw = (uint2*)smem;
  ushort4* s_ci = (ushort4*)(smem + 4608);
  char* sA = smem + 9216;
  char* sB = smem + 17408;
  float* tr = (float*)(smem + 9216);

  const int tid = threadIdx.x;
  const int mblk = blockIdx.x;
  const int b = mblk >> 6, h = mblk & 63;
  const int lane = tid & 63;
  const int wv = tid >> 6;

  for (int i = tid; i < 576; i += 512) {
    int k = i >> 6, pxi = i & 63;
    int o9 = ((b * 9 + k) << 12) + (h << 6) + pxi;
    float m = mskb[o9];
    float py = (float)(h - 1 + k / 3) + dyb[o9];
    float pxf = (float)(pxi - 1 + k % 3) + dxb[o9];
    float y0f = floorf(py), x0f = floorf(pxf);
    float wy = py - y0f, wx = pxf - x0f;
    int y0 = (int)y0f, x0 = (int)x0f;
    int y1 = y0 + 1, x1 = x0 + 1;
    float w00 = (1.f - wy) * (1.f - wx) * m;
    float w01 = (1.f - wy) * wx * m;
    float w10 = wy * (1.f - wx) * m;
    float w11 = wy * wx * m;
    bool vy0 = ((unsigned)y0 < 64u), vy1 = ((unsigned)y1 < 64u);
    bool vx0 = ((unsigned)x0 < 64u), vx1 = ((unsigned)x1 < 64u);
    if (!(vy0 && vx0)) w00 = 0.f;
    if (!(vy0 && vx1)) w01 = 0.f;
    if (!(vy1 && vx0)) w10 = 0.f;
    if (!(vy1 && vx1)) w11 = 0.f;
    int y0c = min(max(y0, 0), 63), y1c = min(max(y1, 0), 63);
    int x0c = min(max(x0, 0), 63), x1c = min(max(x1, 0), 63);
    s_cw[i] = make_uint2(pk2(w00, w01), pk2(w10, w11));
    s_ci[i] = make_ushort4((unsigned short)(y0c * 64 + x0c),
                           (unsigned short)(y0c * 64 + x1c),
                           (unsigned short)(y1c * 64 + x0c),
                           (unsigned short)(y1c * 64 + x1c));
  }
  __syncthreads();

  f32x4 acc[4][2];
#pragma unroll
  for (int mf = 0; mf < 4; ++mf)
#pragma unroll
    for (int nf = 0; nf < 2; ++nf) acc[mf][nf] = (f32x4){0.f, 0.f, 0.f, 0.f};

  const float* xb = x + b * (CI * HWN);
  const int aslot = (lane << 7) + ((wv ^ (lane & 7)) << 4);

  float rx[32];
  float4 cwC;
  {
    uint2 p = s_cw[lane];
    cwC.x = __uint_as_float(p.x << 16);
    cwC.y = __uint_as_float(p.x & 0xffff0000u);
    cwC.z = __uint_as_float(p.y << 16);
    cwC.w = __uint_as_float(p.y & 0xffff0000u);
    ushort4 ci0 = s_ci[lane];
    const float* xpn = xb + (wv << 3) * HWN;
#pragma unroll
    for (int s = 0; s < 8; ++s) {
      const float* xp = xpn + s * HWN;
      rx[4 * s + 0] = xp[ci0.x];
      rx[4 * s + 1] = xp[ci0.y];
      rx[4 * s + 2] = xp[ci0.z];
      rx[4 * s + 3] = xp[ci0.w];
    }
  }

#pragma unroll 1
  for (int t = 0; t < 36; ++t) {
    const int cq = t / 9;
    const int tap = t - cq * 9;
    {
      unsigned pkv[4];
#pragma unroll
      for (int j2 = 0; j2 < 4; ++j2) {
        float v0 = cwC.x * rx[8 * j2 + 0];
        v0 = fmaf(cwC.y, rx[8 * j2 + 1], v0);
        v0 = fmaf(cwC.z, rx[8 * j2 + 2], v0);
        v0 = fmaf(cwC.w, rx[8 * j2 + 3], v0);
        float v1 = cwC.x * rx[8 * j2 + 4];
        v1 = fmaf(cwC.y, rx[8 * j2 + 5], v1);
        v1 = fmaf(cwC.z, rx[8 * j2 + 6], v1);
        v1 = fmaf(cwC.w, rx[8 * j2 + 7], v1);
        pkv[j2] = pk2(v0, v1);
      }
      *(uint4*)(sA + aslot) = make_uint4(pkv[0], pkv[1], pkv[2], pkv[3]);
    }
    {
      const unsigned short* wp = wT + (tap << 16) + (cq << 6);
#pragma unroll
      for (int r = 0; r < 4; ++r) {
        int idx = (r << 9) + tid;
        int o = idx >> 3, seg = idx & 7;
        uint4 v = *(const uint4*)(wp + (o << 8) + (seg << 3));
        int slot = seg ^ (o & 7);
        *(uint4*)(sB + (o << 7) + (slot << 4)) = v;
      }
    }
    {
      const int tn = t < 35 ? t + 1 : 35;
      const int cqn = tn / 9;
      const int tapn = tn - cqn * 9;
      uint2 p = s_cw[(tapn << 6) + lane];
      float4 cwN;
      cwN.x = __uint_as_float(p.x << 16);
      cwN.y = __uint_as_float(p.x & 0xffff0000u);
      cwN.z = __uint_as_float(p.y << 16);
      cwN.w = __uint_as_float(p.y & 0xffff0000u);
      ushort4 ciN = s_ci[(tapn << 6) + lane];
      const float* xpn = xb + (((cqn << 3) + wv) << 3) * HWN;
#pragma unroll
      for (int s = 0; s < 8; ++s) {
        const float* xp = xpn + s * HWN;
        rx[4 * s + 0] = xp[ciN.x];
        rx[4 * s + 1] = xp[ciN.y];
        rx[4 * s + 2] = xp[ciN.z];
        rx[4 * s + 3] = xp[ciN.w];
      }
      cwC = cwN;
    }
    PIPE_BARRIER();
#pragma unroll
    for (int ks = 0; ks < 2; ++ks) {
      bf16x8 af[4], bfr[2];
#pragma unroll
      for (int mf = 0; mf < 4; ++mf) {
        int row = (mf << 4) + (lane & 15);
        int slot = ((ks << 2) + (lane >> 4)) ^ (row & 7);
        af[mf] = *(bf16x8*)(sA + (row << 7) + (slot << 4));
      }
#pragma unroll
      for (int nf = 0; nf < 2; ++nf) {
        int row = (wv << 5) + (nf << 4) + (lane & 15);
        int slot = ((ks << 2) + (lane >> 4)) ^ (row & 7);
        bfr[nf] = *(bf16x8*)(sB + (row << 7) + (slot << 4));
      }
#pragma unroll
      for (int mf = 0; mf < 4; ++mf)
#pragma unroll
        for (int nf = 0; nf < 2; ++nf)
          acc[mf][nf] = __builtin_amdgcn_mfma_f32_16x16x32_bf16(
              af[mf], bfr[nf], acc[mf][nf], 0, 0, 0);
    }
    PIPE_BARRIER();
  }

#pragma unroll
  for (int nf = 0; nf < 2; ++nf) {
    float s = 0.f, q = 0.f;
#pragma unroll
    for (int mf = 0; mf < 4; ++mf)
#pragma unroll
      for (int r = 0; r < 4; ++r) {
        float v = acc[mf][nf][r];
        s += v;
        q = fmaf(v, v, q);
      }
    s += __shfl_down(s, 32);
    q += __shfl_down(q, 32);
    s += __shfl_down(s, 16);
    q += __shfl_down(q, 16);
    if (lane < 16) {
      int o = (wv << 5) + (nf << 4) + lane;
      psum[(o << 9) + mblk] = s;
      psq[(o << 9) + mblk] = q;
    }
  }

  __syncthreads();
  for (int p = 0; p < 2; ++p) {
    if ((wv >> 2) == p) {
#pragma unroll
      for (int mf = 0; mf < 4; ++mf)
#pragma unroll
        for (int nf = 0; nf < 2; ++nf) {
          int ro = ((wv & 3) << 5) + (nf << 4) + (lane & 15);
#pragma unroll
          for (int r = 0; r < 4; ++r)
            tr[ro * 65 + (mf << 4) + ((lane >> 4) << 2) + r] = acc[mf][nf][r];
        }
    }
    __syncthreads();
#pragma unroll
    for (int it = 0; it < 4; ++it) {
      int idx = tid + (it << 9);
      int ro = idx >> 4, qd = idx & 15;
      float4 v = make_float4(tr[ro * 65 + qd * 4], tr[ro * 65 + qd * 4 + 1],
                             tr[ro * 65 + qd * 4 + 2], tr[ro * 65 + qd * 4 + 3]);
      *(float4*)(out + (((b << 8) + (p << 7) + ro) << 12) + (h << 6) +
                 (qd << 2)) = v;
    }
    __syncthreads();
  }
}

// ---------------------------------------------------------------------------
// Kernel 3: per-channel stats -> scale/shift (512 partials per channel).
// ---------------------------------------------------------------------------
__global__ __launch_bounds__(64) void k_stats(
    const float* __restrict__ psum, const float* __restrict__ psq,
    const float* __restrict__ gamma, const float* __restrict__ beta,
    float* __restrict__ scale, float* __restrict__ shift) {
  const int o = blockIdx.x;
  const int t = threadIdx.x;
  float s = 0.f, q = 0.f;
#pragma unroll
  for (int i = 0; i < 8; ++i) {
    s += psum[(o << 9) + t + (i << 6)];
    q += psq[(o << 9) + t + (i << 6)];
  }
#pragma unroll
  for (int off = 32; off > 0; off >>= 1) {
    s += __shfl_down(s, off, 64);
    q += __shfl_down(q, off, 64);
  }
  if (t == 0) {
    const float inv_n = 1.f / 32768.f;
    float mean = s * inv_n;
    float var = fmaf(-mean, mean, q * inv_n);
    float sc = gamma[o] * rsqrtf(var + 1e-5f);
    scale[o] = sc;
    shift[o] = fmaf(-mean, sc, beta[o]);
  }
}

// ---------------------------------------------------------------------------
// Kernel 4: in-place BN + ReLU over d_out (float4 elementwise).
// ---------------------------------------------------------------------------
__global__ __launch_bounds__(256) void k_bnrelu(
    float* __restrict__ out, const float* __restrict__ scale,
    const float* __restrict__ shift) {
  int idx = blockIdx.x * 256 + threadIdx.x;
  int o = (idx >> 10) & 255;
  float sc = scale[o], sh = shift[o];
  float4 v = ((float4*)out)[idx];
  v.x = fmaxf(fmaf(v.x, sc, sh), 0.f);
  v.y = fmaxf(fmaf(v.y, sc, sh), 0.f);
  v.z = fmaxf(fmaf(v.z, sc, sh), 0.f);
  v.w = fmaxf(fmaf(v.w, sc, sh), 0.f);
  ((float4*)out)[idx] = v;
}

extern "C" void kernel_launch(void* const* d_in, const int* in_sizes, int n_in,
                              void* d_out, int out_size, void* d_ws,
                              size_t ws_size, hipStream_t stream) {
  const float* x = (const float*)d_in[0];
  const float* ow = (const float*)d_in[1];
  const float* ob = (const float*)d_in[2];
  const float* mw = (const float*)d_in[3];
  const float* mb = (const float*)d_in[4];
  const float* wgt = (const float*)d_in[5];
  // d_in[6] = conv bias: cancels exactly in BN (out - mean(out)), skipped.
  const float* gamma = (const float*)d_in[7];
  const float* beta = (const float*)d_in[8];
  float* out = (float*)d_out;

  // workspace: proven R5 layout (5.50 MiB) + optional bf16-x copy at tail.
  float* ws = (float*)d_ws;
  float* dyb = ws;                  // 294912
  float* dxb = dyb + 294912;        // 294912
  float* mskb = dxb + 294912;       // 294912
  float* psum = mskb + 294912;      // 256*512 = 131072
  float* psq = psum + 131072;       // 131072
  float* scale = psq + 131072;      // 256
  float* shift = scale + 256;       // 256
  unsigned short* wT = (unsigned short*)(shift + 256);  // 9*256*256 bf16
  unsigned short* xhp = wT + 589824;                    // 8.39M bf16 (opt.)
  const size_t WS_NEED =
      (size_t)(294912 * 3 + 131072 * 2 + 512) * 4 + 589824 * 2 + 8388608 * 2;

  k_wprep<<<256, 256, 0, stream>>>(wgt, wT);
  k_offmod<<<512, 512, 0, stream>>>(x, ow, ob, mw, mb, dyb, dxb, mskb);
  if (ws_size >= WS_NEED) {
    k_xprep<<<4096, 256, 0, stream>>>((const float4*)x, (uint4*)xhp);
    k_main_h<<<512, 512, 0, stream>>>(xhp, wT, dyb, dxb, mskb, out, psum, psq);
  } else {
    k_main_f32<<<512, 512, 0, stream>>>(x, wT, dyb, dxb, mskb, out, psum, psq);
  }
  k_stats<<<256, 64, 0, stream>>>(psum, psq, gamma, beta, scale, shift);
  k_bnrelu<<<8192, 256, 0, stream>>>(out, scale, shift);
}

// Round 12
// 197.010 us; speedup vs baseline: 2.1993x; 1.3167x over previous
//
#include <hip/hip_runtime.h>
#include <math.h>

#define CI 256
#define CO 256
#define HWN 4096  // H*W

typedef short bf16x8 __attribute__((ext_vector_type(8)));
typedef float f32x4 __attribute__((ext_vector_type(4)));

__device__ inline unsigned pk2(float a, float b) {  // RNE pack 2 f32 -> 2 bf16
  unsigned ua = __float_as_uint(a), ub = __float_as_uint(b);
  ua += 0x7fff + ((ua >> 16) & 1);
  ub += 0x7fff + ((ub >> 16) & 1);
  return (ua >> 16) | (ub & 0xffff0000u);
}

// Raw barrier that does NOT drain vmcnt (keeps prefetch loads in flight).
#define PIPE_BARRIER()                                    \
  do {                                                    \
    __builtin_amdgcn_sched_barrier(0);                    \
    asm volatile("s_waitcnt lgkmcnt(0)" ::: "memory");    \
    __builtin_amdgcn_s_barrier();                         \
    __builtin_amdgcn_sched_barrier(0);                    \
  } while (0)

// ---------------------------------------------------------------------------
// Kernel 0a: x f32 -> bf16 (RNE), 8 elements/thread.
// ---------------------------------------------------------------------------
__global__ __launch_bounds__(256) void k_xprep(const float4* __restrict__ xf,
                                               uint4* __restrict__ xh) {
  int i = blockIdx.x * 256 + threadIdx.x;
  float4 a = xf[2 * i], b = xf[2 * i + 1];
  xh[i] = make_uint4(pk2(a.x, a.y), pk2(a.z, a.w), pk2(b.x, b.y),
                     pk2(b.z, b.w));
}

// ---------------------------------------------------------------------------
// Kernel 0b: weight pre-transpose+convert: w[o][c][tap] f32 -> wT[tap][o][c] bf16
// ---------------------------------------------------------------------------
__global__ __launch_bounds__(256) void k_wprep(const float* __restrict__ wgt,
                                               unsigned short* __restrict__ wT) {
  const int o = blockIdx.x, c = threadIdx.x;
  const float* wp = wgt + o * 2304 + c * 9;
  float v[9];
#pragma unroll
  for (int t = 0; t < 9; ++t) v[t] = wp[t];
#pragma unroll
  for (int t = 0; t < 9; ++t) {
    unsigned u = __float_as_uint(v[t]);
    u += 0x7fff + ((u >> 16) & 1);
    wT[(t << 16) + (o << 8) + c] = (unsigned short)(u >> 16);
  }
}

// ---------------------------------------------------------------------------
// Kernel 0c: offset/mod weights -> wTo[tap][32][256] bf16 (rows 27..31 = 0).
// Row o<18: ow channel o; 18<=o<27: mw channel o-18.
// ---------------------------------------------------------------------------
__global__ __launch_bounds__(256) void k_woprep(
    const float* __restrict__ ow, const float* __restrict__ mw,
    unsigned short* __restrict__ wTo) {
  const int o = blockIdx.x, c = threadIdx.x;
  float v[9];
  if (o < 18) {
    const float* wp = ow + o * 2304 + c * 9;
#pragma unroll
    for (int t = 0; t < 9; ++t) v[t] = wp[t];
  } else if (o < 27) {
    const float* wp = mw + (o - 18) * 2304 + c * 9;
#pragma unroll
    for (int t = 0; t < 9; ++t) v[t] = wp[t];
  } else {
#pragma unroll
    for (int t = 0; t < 9; ++t) v[t] = 0.f;
  }
#pragma unroll
  for (int t = 0; t < 9; ++t) {
    unsigned u = __float_as_uint(v[t]);
    u += 0x7fff + ((u >> 16) & 1);
    wTo[(t << 13) + (o << 8) + c] = (unsigned short)(u >> 16);
  }
}

// ---------------------------------------------------------------------------
// Kernel 1 (MFMA): offset+mod conv as a static-tap gather-GEMM, structural
// copy of the proven k_main_h pipeline. Block = 256 thr / 4 waves = one (b,h)
// row (64 px) x 32 outputs (27 real). Wave wv owns px [wv*16,+16), nf 0..1.
// Static taps: wy=wx=0 -> sample = a*lo(d)+b*hi(d) of ONE dword of bf16-x
// (pair-select, clamp/validity folded into a,b). A-loads are lane-adjacent
// (coalesced). Epilogue: bias + (sigmoid for mask) -> dyb/dxb/mskb planes.
// ---------------------------------------------------------------------------
__global__ __launch_bounds__(256, 4) void k_offmod_m(
    const unsigned short* __restrict__ xh, const unsigned short* __restrict__ wTo,
    const float* __restrict__ ob, const float* __restrict__ mb,
    float* __restrict__ dyb, float* __restrict__ dxb,
    float* __restrict__ mskb) {
  __shared__ __align__(16) unsigned s_cwo[576];   // [9][64] (a,b) bf16 pair
  __shared__ unsigned short s_cio[576];           // [9][64] dword base idx
  __shared__ __align__(16) char sA[8192];         // 64px x 64ch bf16, swizzled
  __shared__ __align__(16) char sB[4096];         // 32o x 64ch bf16, swizzled

  const int tid = threadIdx.x;
  const int bid = blockIdx.x;  // b*64 + h (same ordering as k_main_h)
  const int b = bid >> 6, h = bid & 63;
  const int lane = tid & 63;
  const int wv = tid >> 6;  // 0..3: MFMA px-frag owner AND staging group
  const int px = lane;      // staging pixel (tid&63)

  // ---- static corner table: 9 taps * 64 px ----
  for (int i = tid; i < 576; i += 256) {
    int k = i >> 6, pxi = i & 63;
    int ky = k / 3, kx = k - 3 * ky;
    int y0 = h - 1 + ky;
    int x0 = pxi - 1 + kx;
    bool vy = ((unsigned)y0 < 64u);
    bool vx = ((unsigned)x0 < 64u);
    float w00 = (vy && vx) ? 1.f : 0.f;
    int y0c = min(max(y0, 0), 63);
    int xp = min(max(x0, 0), 62);
    int s0 = min(max(x0, 0), 63) - xp;  // 0 or 1
    float a = s0 ? 0.f : w00;
    float bb = s0 ? w00 : 0.f;
    s_cwo[i] = pk2(a, bb);
    s_cio[i] = (unsigned short)(y0c * 64 + xp);
  }
  __syncthreads();

  f32x4 acc[2];
  acc[0] = (f32x4){0.f, 0.f, 0.f, 0.f};
  acc[1] = (f32x4){0.f, 0.f, 0.f, 0.f};

  const char* xbh = (const char*)(xh + (size_t)b * (CI * HWN));

  // ---- prologue: chunk 0 (cq=0, tap=0) corners + 16 dword loads ----
  unsigned rxu[16];
  float cwA, cwB;
  {
    unsigned p = s_cwo[px];
    cwA = __uint_as_float(p << 16);
    cwB = __uint_as_float(p & 0xffff0000u);
    int ci = s_cio[px];
#pragma unroll
    for (int g2 = 0; g2 < 2; ++g2) {
      int g = wv + (g2 << 2);
#pragma unroll
      for (int j = 0; j < 8; ++j) {
        int c = (g << 3) + j;
        __builtin_memcpy(&rxu[(g2 << 3) + j], xbh + (((c << 12) + ci) << 1), 4);
      }
    }
  }

#pragma unroll 1
  for (int t = 0; t < 36; ++t) {
    const int cq = t / 9;
    const int tap = t - cq * 9;
    // ---- pack 16 prefetched samples -> sA (2 uint4 writes) ----
#pragma unroll
    for (int g2 = 0; g2 < 2; ++g2) {
      unsigned pkv[4];
#pragma unroll
      for (int j2 = 0; j2 < 4; ++j2) {
        unsigned d0 = rxu[(g2 << 3) + (j2 << 1)];
        unsigned d1 = rxu[(g2 << 3) + (j2 << 1) + 1];
        float v0 = cwA * __uint_as_float(d0 << 16);
        v0 = fmaf(cwB, __uint_as_float(d0 & 0xffff0000u), v0);
        float v1 = cwA * __uint_as_float(d1 << 16);
        v1 = fmaf(cwB, __uint_as_float(d1 & 0xffff0000u), v1);
        pkv[j2] = pk2(v0, v1);
      }
      int g = wv + (g2 << 2);
      *(uint4*)(sA + (px << 7) + ((g ^ (px & 7)) << 4)) =
          make_uint4(pkv[0], pkv[1], pkv[2], pkv[3]);
    }
    // ---- stage B: wTo[tap][0..31][cq*64..+64], one uint4/thread ----
    {
      int o = tid >> 3, seg = tid & 7;
      uint4 v = *(const uint4*)(wTo + (tap << 13) + (o << 8) + (cq << 6) +
                                (seg << 3));
      *(uint4*)(sB + (o << 7) + ((seg ^ (o & 7)) << 4)) = v;
    }
    // ---- prefetch chunk t+1 ----
    {
      const int tn = t < 35 ? t + 1 : 35;
      const int cqn = tn / 9;
      const int tapn = tn - cqn * 9;
      unsigned p = s_cwo[(tapn << 6) + px];
      float cwAn = __uint_as_float(p << 16);
      float cwBn = __uint_as_float(p & 0xffff0000u);
      int ci = s_cio[(tapn << 6) + px];
#pragma unroll
      for (int g2 = 0; g2 < 2; ++g2) {
        int g = wv + (g2 << 2);
#pragma unroll
        for (int j = 0; j < 8; ++j) {
          int c = (cqn << 6) + (g << 3) + j;
          __builtin_memcpy(&rxu[(g2 << 3) + j], xbh + (((c << 12) + ci) << 1),
                           4);
        }
      }
      cwA = cwAn;
      cwB = cwBn;
    }
    PIPE_BARRIER();  // sA/sB visible; prefetch loads in flight
    // ---- MFMA: 2 k-steps x 1 mfrag(=wv) x 2 nfrag ----
#pragma unroll
    for (int ks = 0; ks < 2; ++ks) {
      int arow = (wv << 4) + (lane & 15);
      int aslt = ((ks << 2) + (lane >> 4)) ^ (arow & 7);
      bf16x8 af = *(bf16x8*)(sA + (arow << 7) + (aslt << 4));
#pragma unroll
      for (int nf = 0; nf < 2; ++nf) {
        int brow = (nf << 4) + (lane & 15);
        int bslt = ((ks << 2) + (lane >> 4)) ^ (brow & 7);
        bf16x8 bfr = *(bf16x8*)(sB + (brow << 7) + (bslt << 4));
        acc[nf] = __builtin_amdgcn_mfma_f32_16x16x32_bf16(af, bfr, acc[nf], 0,
                                                          0, 0);
      }
    }
    PIPE_BARRIER();  // frag reads done before next writes
  }

  // ---- epilogue: D col=lane&15 -> o, row=(lane>>4)*4+r -> px ----
#pragma unroll
  for (int nf = 0; nf < 2; ++nf) {
    int o = (nf << 4) + (lane & 15);
    int px0 = (wv << 4) + ((lane >> 4) << 2);
    if (o < 18) {
      float bo = ob[o];
      float4 v = make_float4(acc[nf][0] + bo, acc[nf][1] + bo, acc[nf][2] + bo,
                             acc[nf][3] + bo);
      float* dst = (o & 1) ? dxb : dyb;
      int k = o >> 1;
      *(float4*)(dst + ((b * 9 + k) << 12) + (h << 6) + px0) = v;
    } else if (o < 27) {
      float bm = mb[o - 18];
      float4 v;
      v.x = 2.f / (1.f + expf(-(acc[nf][0] + bm)));
      v.y = 2.f / (1.f + expf(-(acc[nf][1] + bm)));
      v.z = 2.f / (1.f + expf(-(acc[nf][2] + bm)));
      v.w = 2.f / (1.f + expf(-(acc[nf][3] + bm)));
      *(float4*)(mskb + ((b * 9 + (o - 18)) << 12) + (h << 6) + px0) = v;
    }
  }
}

// ---------------------------------------------------------------------------
// Kernel 1 fallback (f32 x, shfl version) for small-ws path. R11-exact.
// ---------------------------------------------------------------------------
__global__ __launch_bounds__(512, 4) void k_offmod_fb(
    const float* __restrict__ x, const float* __restrict__ ow,
    const float* __restrict__ ob, const float* __restrict__ mw,
    const float* __restrict__ mb, float* __restrict__ dyb,
    float* __restrict__ dxb, float* __restrict__ mskb) {
  __shared__ float ps[13824];
  const int tid = threadIdx.x;
  const int bid = blockIdx.x;
  const int b = bid & 7;
  const int h = bid >> 3;
  const int cg = __builtin_amdgcn_readfirstlane(tid >> 6);
  const int px = tid & 63;
  float acc[27];
#pragma unroll
  for (int i = 0; i < 27; ++i) acc[i] = 0.f;

  const float* xb = x + b * (CI * HWN);
  const int h0c = max(h - 1, 0), h2c = min(h + 1, 63);
  const bool v0 = h > 0, v2 = h < 63;
  const bool e0 = (px == 0), e63 = (px == 63);
  const float* xw = xb + (cg << 5) * HWN;

#pragma unroll 1
  for (int i = 0; i < 32; ++i) {
    const float* xc = xw + i * HWN;
    float c0 = xc[h0c * 64 + px];
    float c1 = xc[h * 64 + px];
    float c2 = xc[h2c * 64 + px];
    c0 = v0 ? c0 : 0.f;
    c2 = v2 ? c2 : 0.f;
    float l0 = __shfl_up(c0, 1), l1 = __shfl_up(c1, 1), l2 = __shfl_up(c2, 1);
    float r0 = __shfl_down(c0, 1), r1 = __shfl_down(c1, 1),
          r2 = __shfl_down(c2, 1);
    l0 = e0 ? 0.f : l0;
    l1 = e0 ? 0.f : l1;
    l2 = e0 ? 0.f : l2;
    r0 = e63 ? 0.f : r0;
    r1 = e63 ? 0.f : r1;
    r2 = e63 ? 0.f : r2;
    float xv[9] = {l0, c0, r0, l1, c1, r1, l2, c2, r2};
    const int c = (cg << 5) + i;
    const float* owp = ow + c * 9;
    const float* mwp = mw + c * 9;
#pragma unroll
    for (int ch = 0; ch < 18; ++ch)
#pragma unroll
      for (int k = 0; k < 9; ++k)
        acc[ch] = fmaf(owp[ch * 2304 + k], xv[k], acc[ch]);
#pragma unroll
    for (int ch = 0; ch < 9; ++ch)
#pragma unroll
      for (int k = 0; k < 9; ++k)
        acc[18 + ch] = fmaf(mwp[ch * 2304 + k], xv[k], acc[18 + ch]);
  }

#pragma unroll
  for (int ch = 0; ch < 27; ++ch) ps[(px * 27 + ch) * 8 + cg] = acc[ch];
  __syncthreads();
  for (int i = tid; i < 1728; i += 512) {
    int p2 = i / 27;
    int ch = i - p2 * 27;
    float s = 0.f;
#pragma unroll
    for (int g = 0; g < 8; ++g) s += ps[i * 8 + g];
    if (ch < 18) {
      s += ob[ch];
      int k = ch >> 1;
      int o9 = ((b * 9 + k) << 12) + (h << 6) + p2;
      if ((ch & 1) == 0) dyb[o9] = s;
      else dxb[o9] = s;
    } else {
      int k = ch - 18;
      s += mb[k];
      mskb[((b * 9 + k) << 12) + (h << 6) + p2] = 2.f / (1.f + expf(-s));
    }
  }
}

// ---------------------------------------------------------------------------
// Kernel 2 (bf16-x path): R10-exact pair-gather MFMA GEMM.
// ---------------------------------------------------------------------------
__global__ __launch_bounds__(512, 4) void k_main_h(
    const unsigned short* __restrict__ xh, const unsigned short* __restrict__ wT,
    const float* __restrict__ dyb, const float* __restrict__ dxb,
    const float* __restrict__ mskb, float* __restrict__ out,
    float* __restrict__ psum, float* __restrict__ psq) {
  __shared__ __align__(16) char smem[47872];
  uint2* s_cw = (uint2*)smem;                // [9][64] a0b0|a1b1 bf16, 4608 B
  ushort2* s_ci = (ushort2*)(smem + 4608);   // [9][64] pair bases, 2304 B
  char* sA = smem + 6912;                    // 64x64 bf16 = 8192 B
  char* sB = smem + 15104;                   // 256x64 bf16 = 32768 B
  float* tr = (float*)(smem + 6912);         // epilogue reuse: 128*65*4 B

  const int tid = threadIdx.x;
  const int mblk = blockIdx.x;  // b*64 + h
  const int b = mblk >> 6, h = mblk & 63;
  const int lane = tid & 63;
  const int wv = tid >> 6;

  // ---- corner table: 9 taps * 64 px, pair form ----
  for (int i = tid; i < 576; i += 512) {
    int k = i >> 6, pxi = i & 63;
    int o9 = ((b * 9 + k) << 12) + (h << 6) + pxi;
    float m = mskb[o9];
    float py = (float)(h - 1 + k / 3) + dyb[o9];
    float pxf = (float)(pxi - 1 + k % 3) + dxb[o9];
    float y0f = floorf(py), x0f = floorf(pxf);
    float wy = py - y0f, wx = pxf - x0f;
    int y0 = (int)y0f, x0 = (int)x0f;
    int y1 = y0 + 1, x1 = x0 + 1;
    float w00 = (1.f - wy) * (1.f - wx) * m;
    float w01 = (1.f - wy) * wx * m;
    float w10 = wy * (1.f - wx) * m;
    float w11 = wy * wx * m;
    bool vy0 = ((unsigned)y0 < 64u), vy1 = ((unsigned)y1 < 64u);
    bool vx0 = ((unsigned)x0 < 64u), vx1 = ((unsigned)x1 < 64u);
    if (!(vy0 && vx0)) w00 = 0.f;
    if (!(vy0 && vx1)) w01 = 0.f;
    if (!(vy1 && vx0)) w10 = 0.f;
    if (!(vy1 && vx1)) w11 = 0.f;
    int y0c = min(max(y0, 0), 63), y1c = min(max(y1, 0), 63);
    int x0c = min(max(x0, 0), 63), x1c = min(max(x1, 0), 63);
    int xp = min(max(x0, 0), 62);
    int s0 = x0c - xp, s1 = x1c - xp;  // each in {0,1}
    float a0 = (s0 ? 0.f : w00) + (s1 ? 0.f : w01);
    float b0 = (s0 ? w00 : 0.f) + (s1 ? w01 : 0.f);
    float a1 = (s0 ? 0.f : w10) + (s1 ? 0.f : w11);
    float b1 = (s0 ? w10 : 0.f) + (s1 ? w11 : 0.f);
    s_cw[i] = make_uint2(pk2(a0, b0), pk2(a1, b1));
    s_ci[i] = make_ushort2((unsigned short)(y0c * 64 + xp),
                           (unsigned short)(y1c * 64 + xp));
  }
  __syncthreads();

  f32x4 acc[4][2];
#pragma unroll
  for (int mf = 0; mf < 4; ++mf)
#pragma unroll
    for (int nf = 0; nf < 2; ++nf) acc[mf][nf] = (f32x4){0.f, 0.f, 0.f, 0.f};

  const char* xbh = (const char*)(xh + (size_t)b * (CI * HWN));
  const int aslot = (lane << 7) + ((wv ^ (lane & 7)) << 4);

  // ---- prologue: corner regs + pair-prefetch for chunk 0 (cq=0, tap=0) ----
  unsigned rxu[16];  // [s][row]: 8 samples x 2 dwords
  float4 cwC;
  {
    uint2 p = s_cw[lane];
    cwC.x = __uint_as_float(p.x << 16);
    cwC.y = __uint_as_float(p.x & 0xffff0000u);
    cwC.z = __uint_as_float(p.y << 16);
    cwC.w = __uint_as_float(p.y & 0xffff0000u);
    ushort2 ci0 = s_ci[lane];
    const char* xcn = xbh + (((wv << 3) * HWN) << 1);
#pragma unroll
    for (int s = 0; s < 8; ++s) {
      const char* xc = xcn + ((s * HWN) << 1);
      __builtin_memcpy(&rxu[2 * s + 0], xc + ((int)ci0.x << 1), 4);
      __builtin_memcpy(&rxu[2 * s + 1], xc + ((int)ci0.y << 1), 4);
    }
  }

#pragma unroll 1
  for (int t = 0; t < 36; ++t) {
    const int cq = t / 9;
    const int tap = t - cq * 9;
    // ---- pack chunk t's prefetched pairs -> sA ----
    {
      unsigned pkv[4];
#pragma unroll
      for (int j2 = 0; j2 < 4; ++j2) {
        float vv[2];
#pragma unroll
        for (int u = 0; u < 2; ++u) {
          unsigned d0 = rxu[4 * j2 + 2 * u], d1 = rxu[4 * j2 + 2 * u + 1];
          float v = cwC.x * __uint_as_float(d0 << 16);
          v = fmaf(cwC.y, __uint_as_float(d0 & 0xffff0000u), v);
          v = fmaf(cwC.z, __uint_as_float(d1 << 16), v);
          vv[u] = fmaf(cwC.w, __uint_as_float(d1 & 0xffff0000u), v);
        }
        pkv[j2] = pk2(vv[0], vv[1]);
      }
      *(uint4*)(sA + aslot) = make_uint4(pkv[0], pkv[1], pkv[2], pkv[3]);
    }
    // ---- stage B: coalesced copy wT[tap][0..255][cq*64..+64] ----
    {
      const unsigned short* wp = wT + (tap << 16) + (cq << 6);
#pragma unroll
      for (int r = 0; r < 4; ++r) {
        int idx = (r << 9) + tid;  // 0..2047
        int o = idx >> 3, seg = idx & 7;
        uint4 v = *(const uint4*)(wp + (o << 8) + (seg << 3));
        int slot = seg ^ (o & 7);
        *(uint4*)(sB + (o << 7) + (slot << 4)) = v;
      }
    }
    // ---- prefetch chunk t+1: next tap's corner regs + 16 pair-loads ----
    {
      const int tn = t < 35 ? t + 1 : 35;  // clamp: last iter reloads (unused)
      const int cqn = tn / 9;
      const int tapn = tn - cqn * 9;
      uint2 p = s_cw[(tapn << 6) + lane];
      float4 cwN;
      cwN.x = __uint_as_float(p.x << 16);
      cwN.y = __uint_as_float(p.x & 0xffff0000u);
      cwN.z = __uint_as_float(p.y << 16);
      cwN.w = __uint_as_float(p.y & 0xffff0000u);
      ushort2 ciN = s_ci[(tapn << 6) + lane];
      const char* xcn = xbh + ((((cqn << 3) + wv) << 3) * HWN << 1);
#pragma unroll
      for (int s = 0; s < 8; ++s) {
        const char* xc = xcn + ((s * HWN) << 1);
        __builtin_memcpy(&rxu[2 * s + 0], xc + ((int)ciN.x << 1), 4);
        __builtin_memcpy(&rxu[2 * s + 1], xc + ((int)ciN.y << 1), 4);
      }
      cwC = cwN;
    }
    PIPE_BARRIER();  // sA/sB visible; prefetch loads stay in flight
    // ---- MFMA: 2 k-steps x 4 mfrag x 2 nfrag ----
#pragma unroll
    for (int ks = 0; ks < 2; ++ks) {
      bf16x8 af[4], bfr[2];
#pragma unroll
      for (int mf = 0; mf < 4; ++mf) {
        int row = (mf << 4) + (lane & 15);
        int slot = ((ks << 2) + (lane >> 4)) ^ (row & 7);
        af[mf] = *(bf16x8*)(sA + (row << 7) + (slot << 4));
      }
#pragma unroll
      for (int nf = 0; nf < 2; ++nf) {
        int row = (wv << 5) + (nf << 4) + (lane & 15);
        int slot = ((ks << 2) + (lane >> 4)) ^ (row & 7);
        bfr[nf] = *(bf16x8*)(sB + (row << 7) + (slot << 4));
      }
#pragma unroll
      for (int mf = 0; mf < 4; ++mf)
#pragma unroll
        for (int nf = 0; nf < 2; ++nf)
          acc[mf][nf] = __builtin_amdgcn_mfma_f32_16x16x32_bf16(
              af[mf], bfr[nf], acc[mf][nf], 0, 0, 0);
    }
    PIPE_BARRIER();  // frag reads done before next iteration's writes
  }

  // ---- BN partial stats from registers ----
#pragma unroll
  for (int nf = 0; nf < 2; ++nf) {
    float s = 0.f, q = 0.f;
#pragma unroll
    for (int mf = 0; mf < 4; ++mf)
#pragma unroll
      for (int r = 0; r < 4; ++r) {
        float v = acc[mf][nf][r];
        s += v;
        q = fmaf(v, v, q);
      }
    s += __shfl_down(s, 32);
    q += __shfl_down(q, 32);
    s += __shfl_down(s, 16);
    q += __shfl_down(q, 16);
    if (lane < 16) {
      int o = (wv << 5) + (nf << 4) + lane;
      psum[(o << 9) + mblk] = s;
      psq[(o << 9) + mblk] = q;
    }
  }

  // ---- store via LDS transpose, 2 passes of 128 o-rows ----
  __syncthreads();
  for (int p = 0; p < 2; ++p) {
    if ((wv >> 2) == p) {
#pragma unroll
      for (int mf = 0; mf < 4; ++mf)
#pragma unroll
        for (int nf = 0; nf < 2; ++nf) {
          int ro = ((wv & 3) << 5) + (nf << 4) + (lane & 15);
#pragma unroll
          for (int r = 0; r < 4; ++r)
            tr[ro * 65 + (mf << 4) + ((lane >> 4) << 2) + r] = acc[mf][nf][r];
        }
    }
    __syncthreads();
#pragma unroll
    for (int it = 0; it < 4; ++it) {
      int idx = tid + (it << 9);
      int ro = idx >> 4, qd = idx & 15;
      float4 v = make_float4(tr[ro * 65 + qd * 4], tr[ro * 65 + qd * 4 + 1],
                             tr[ro * 65 + qd * 4 + 2], tr[ro * 65 + qd * 4 + 3]);
      *(float4*)(out + (((b << 8) + (p << 7) + ro) << 12) + (h << 6) +
                 (qd << 2)) = v;
    }
    __syncthreads();
  }
}

// ---------------------------------------------------------------------------
// Kernel 2 fallback (f32 x): R5-exact k_main for small-ws path.
// ---------------------------------------------------------------------------
__global__ __launch_bounds__(512, 4) void k_main_f32(
    const float* __restrict__ x, const unsigned short* __restrict__ wT,
    const float* __restrict__ dyb, const float* __restrict__ dxb,
    const float* __restrict__ mskb, float* __restrict__ out,
    float* __restrict__ psum, float* __restrict__ psq) {
  __shared__ __align__(16) char smem[50176];
  uint2* s_cw = (uint2*)smem;
  ushort4* s_ci = (ushort4*)(smem + 4608);
  char* sA = smem + 9216;
  char* sB = smem + 17408;
  float* tr = (float*)(smem + 9216);

  const int tid = threadIdx.x;
  const int mblk = blockIdx.x;
  const int b = mblk >> 6, h = mblk & 63;
  const int lane = tid & 63;
  const int wv = tid >> 6;

  for (int i = tid; i < 576; i += 512) {
    int k = i >> 6, pxi = i & 63;
    int o9 = ((b * 9 + k) << 12) + (h << 6) + pxi;
    float m = mskb[o9];
    float py = (float)(h - 1 + k / 3) + dyb[o9];
    float pxf = (float)(pxi - 1 + k % 3) + dxb[o9];
    float y0f = floorf(py), x0f = floorf(pxf);
    float wy = py - y0f, wx = pxf - x0f;
    int y0 = (int)y0f, x0 = (int)x0f;
    int y1 = y0 + 1, x1 = x0 + 1;
    float w00 = (1.f - wy) * (1.f - wx) * m;
    float w01 = (1.f - wy) * wx * m;
    float w10 = wy * (1.f - wx) * m;
    float w11 = wy * wx * m;
    bool vy0 = ((unsigned)y0 < 64u), vy1 = ((unsigned)y1 < 64u);
    bool vx0 = ((unsigned)x0 < 64u), vx1 = ((unsigned)x1 < 64u);
    if (!(vy0 && vx0)) w00 = 0.f;
    if (!(vy0 && vx1)) w01 = 0.f;
    if (!(vy1 && vx0)) w10 = 0.f;
    if (!(vy1 && vx1)) w11 = 0.f;
    int y0c = min(max(y0, 0), 63), y1c = min(max(y1, 0), 63);
    int x0c = min(max(x0, 0), 63), x1c = min(max(x1, 0), 63);
    s_cw[i] = make_uint2(pk2(w00, w01), pk2(w10, w11));
    s_ci[i] = make_ushort4((unsigned short)(y0c * 64 + x0c),
                           (unsigned short)(y0c * 64 + x1c),
                           (unsigned short)(y1c * 64 + x0c),
                           (unsigned short)(y1c * 64 + x1c));
  }
  __syncthreads();

  f32x4 acc[4][2];
#pragma unroll
  for (int mf = 0; mf < 4; ++mf)
#pragma unroll
    for (int nf = 0; nf < 2; ++nf) acc[mf][nf] = (f32x4){0.f, 0.f, 0.f, 0.f};

  const float* xb = x + b * (CI * HWN);
  const int aslot = (lane << 7) + ((wv ^ (lane & 7)) << 4);

  float rx[32];
  float4 cwC;
  {
    uint2 p = s_cw[lane];
    cwC.x = __uint_as_float(p.x << 16);
    cwC.y = __uint_as_float(p.x & 0xffff0000u);
    cwC.z = __uint_as_float(p.y << 16);
    cwC.w = __uint_as_float(p.y & 0xffff0000u);
    ushort4 ci0 = s_ci[lane];
    const float* xpn = xb + (wv << 3) * HWN;
#pragma unroll
    for (int s = 0; s < 8; ++s) {
      const float* xp = xpn + s * HWN;
      rx[4 * s + 0] = xp[ci0.x];
      rx[4 * s + 1] = xp[ci0.y];
      rx[4 * s + 2] = xp[ci0.z];
      rx[4 * s + 3] = xp[ci0.w];
    }
  }

#pragma unroll 1
  for (int t = 0; t < 36; ++t) {
    const int cq = t / 9;
    const int tap = t - cq * 9;
    {
      unsigned pkv[4];
#pragma unroll
      for (int j2 = 0; j2 < 4; ++j2) {
        float v0 = cwC.x * rx[8 * j2 + 0];
        v0 = fmaf(cwC.y, rx[8 * j2 + 1], v0);
        v0 = fmaf(cwC.z, rx[8 * j2 + 2], v0);
        v0 = fmaf(cwC.w, rx[8 * j2 + 3], v0);
        float v1 = cwC.x * rx[8 * j2 + 4];
        v1 = fmaf(cwC.y, rx[8 * j2 + 5], v1);
        v1 = fmaf(cwC.z, rx[8 * j2 + 6], v1);
        v1 = fmaf(cwC.w, rx[8 * j2 + 7], v1);
        pkv[j2] = pk2(v0, v1);
      }
      *(uint4*)(sA + aslot) = make_uint4(pkv[0], pkv[1], pkv[2], pkv[3]);
    }
    {
      const unsigned short* wp = wT + (tap << 16) + (cq << 6);
#pragma unroll
      for (int r = 0; r < 4; ++r) {
        int idx = (r << 9) + tid;
        int o = idx >> 3, seg = idx & 7;
        uint4 v = *(const uint4*)(wp + (o << 8) + (seg << 3));
        int slot = seg ^ (o & 7);
        *(uint4*)(sB + (o << 7) + (slot << 4)) = v;
      }
    }
    {
      const int tn = t < 35 ? t + 1 : 35;
      const int cqn = tn / 9;
      const int tapn = tn - cqn * 9;
      uint2 p = s_cw[(tapn << 6) + lane];
      float4 cwN;
      cwN.x = __uint_as_float(p.x << 16);
      cwN.y = __uint_as_float(p.x & 0xffff0000u);
      cwN.z = __uint_as_float(p.y << 16);
      cwN.w = __uint_as_float(p.y & 0xffff0000u);
      ushort4 ciN = s_ci[(tapn << 6) + lane];
      const float* xpn = xb + (((cqn << 3) + wv) << 3) * HWN;
#pragma unroll
      for (int s = 0; s < 8; ++s) {
        const float* xp = xpn + s * HWN;
        rx[4 * s + 0] = xp[ciN.x];
        rx[4 * s + 1] = xp[ciN.y];
        rx[4 * s + 2] = xp[ciN.z];
        rx[4 * s + 3] = xp[ciN.w];
      }
      cwC = cwN;
    }
    PIPE_BARRIER();
#pragma unroll
    for (int ks = 0; ks < 2; ++ks) {
      bf16x8 af[4], bfr[2];
#pragma unroll
      for (int mf = 0; mf < 4; ++mf) {
        int row = (mf << 4) + (lane & 15);
        int slot = ((ks << 2) + (lane >> 4)) ^ (row & 7);
        af[mf] = *(bf16x8*)(sA + (row << 7) + (slot << 4));
      }
#pragma unroll
      for (int nf = 0; nf < 2; ++nf) {
        int row = (wv << 5) + (nf << 4) + (lane & 15);
        int slot = ((ks << 2) + (lane >> 4)) ^ (row & 7);
        bfr[nf] = *(bf16x8*)(sB + (row << 7) + (slot << 4));
      }
#pragma unroll
      for (int mf = 0; mf < 4; ++mf)
#pragma unroll
        for (int nf = 0; nf < 2; ++nf)
          acc[mf][nf] = __builtin_amdgcn_mfma_f32_16x16x32_bf16(
              af[mf], bfr[nf], acc[mf][nf], 0, 0, 0);
    }
    PIPE_BARRIER();
  }

#pragma unroll
  for (int nf = 0; nf < 2; ++nf) {
    float s = 0.f, q = 0.f;
#pragma unroll
    for (int mf = 0; mf < 4; ++mf)
#pragma unroll
      for (int r = 0; r < 4; ++r) {
        float v = acc[mf][nf][r];
        s += v;
        q = fmaf(v, v, q);
      }
    s += __shfl_down(s, 32);
    q += __shfl_down(q, 32);
    s += __shfl_down(s, 16);
    q += __shfl_down(q, 16);
    if (lane < 16) {
      int o = (wv << 5) + (nf << 4) + lane;
      psum[(o << 9) + mblk] = s;
      psq[(o << 9) + mblk] = q;
    }
  }

  __syncthreads();
  for (int p = 0; p < 2; ++p) {
    if ((wv >> 2) == p) {
#pragma unroll
      for (int mf = 0; mf < 4; ++mf)
#pragma unroll
        for (int nf = 0; nf < 2; ++nf) {
          int ro = ((wv & 3) << 5) + (nf << 4) + (lane & 15);
#pragma unroll
          for (int r = 0; r < 4; ++r)
            tr[ro * 65 + (mf << 4) + ((lane >> 4) << 2) + r] = acc[mf][nf][r];
        }
    }
    __syncthreads();
#pragma unroll
    for (int it = 0; it < 4; ++it) {
      int idx = tid + (it << 9);
      int ro = idx >> 4, qd = idx & 15;
      float4 v = make_float4(tr[ro * 65 + qd * 4], tr[ro * 65 + qd * 4 + 1],
                             tr[ro * 65 + qd * 4 + 2], tr[ro * 65 + qd * 4 + 3]);
      *(float4*)(out + (((b << 8) + (p << 7) + ro) << 12) + (h << 6) +
                 (qd << 2)) = v;
    }
    __syncthreads();
  }
}

// ---------------------------------------------------------------------------
// Kernel 3: per-channel stats -> scale/shift (512 partials per channel).
// ---------------------------------------------------------------------------
__global__ __launch_bounds__(64) void k_stats(
    const float* __restrict__ psum, const float* __restrict__ psq,
    const float* __restrict__ gamma, const float* __restrict__ beta,
    float* __restrict__ scale, float* __restrict__ shift) {
  const int o = blockIdx.x;
  const int t = threadIdx.x;
  float s = 0.f, q = 0.f;
#pragma unroll
  for (int i = 0; i < 8; ++i) {
    s += psum[(o << 9) + t + (i << 6)];
    q += psq[(o << 9) + t + (i << 6)];
  }
#pragma unroll
  for (int off = 32; off > 0; off >>= 1) {
    s += __shfl_down(s, off, 64);
    q += __shfl_down(q, off, 64);
  }
  if (t == 0) {
    const float inv_n = 1.f / 32768.f;
    float mean = s * inv_n;
    float var = fmaf(-mean, mean, q * inv_n);
    float sc = gamma[o] * rsqrtf(var + 1e-5f);
    scale[o] = sc;
    shift[o] = fmaf(-mean, sc, beta[o]);
  }
}

// ---------------------------------------------------------------------------
// Kernel 4: in-place BN + ReLU over d_out (float4 elementwise).
// ---------------------------------------------------------------------------
__global__ __launch_bounds__(256) void k_bnrelu(
    float* __restrict__ out, const float* __restrict__ scale,
    const float* __restrict__ shift) {
  int idx = blockIdx.x * 256 + threadIdx.x;
  int o = (idx >> 10) & 255;
  float sc = scale[o], sh = shift[o];
  float4 v = ((float4*)out)[idx];
  v.x = fmaxf(fmaf(v.x, sc, sh), 0.f);
  v.y = fmaxf(fmaf(v.y, sc, sh), 0.f);
  v.z = fmaxf(fmaf(v.z, sc, sh), 0.f);
  v.w = fmaxf(fmaf(v.w, sc, sh), 0.f);
  ((float4*)out)[idx] = v;
}

extern "C" void kernel_launch(void* const* d_in, const int* in_sizes, int n_in,
                              void* d_out, int out_size, void* d_ws,
                              size_t ws_size, hipStream_t stream) {
  const float* x = (const float*)d_in[0];
  const float* ow = (const float*)d_in[1];
  const float* ob = (const float*)d_in[2];
  const float* mw = (const float*)d_in[3];
  const float* mb = (const float*)d_in[4];
  const float* wgt = (const float*)d_in[5];
  // d_in[6] = conv bias: cancels exactly in BN (out - mean(out)), skipped.
  const float* gamma = (const float*)d_in[7];
  const float* beta = (const float*)d_in[8];
  float* out = (float*)d_out;

  // workspace: R5 core (5.50 MiB) + bf16-x (16 MiB) + wTo (144 KiB) at tail.
  float* ws = (float*)d_ws;
  float* dyb = ws;                  // 294912
  float* dxb = dyb + 294912;        // 294912
  float* mskb = dxb + 294912;       // 294912
  float* psum = mskb + 294912;      // 256*512 = 131072
  float* psq = psum + 131072;       // 131072
  float* scale = psq + 131072;      // 256
  float* shift = scale + 256;       // 256
  unsigned short* wT = (unsigned short*)(shift + 256);  // 9*256*256 bf16
  unsigned short* xhp = wT + 589824;                    // 8.39M bf16
  unsigned short* wTo = xhp + 8388608;                  // 9*32*256 bf16
  const size_t WS_NEED = (size_t)(294912 * 3 + 131072 * 2 + 512) * 4 +
                         589824 * 2 + 8388608 * 2 + 73728 * 2;

  k_wprep<<<256, 256, 0, stream>>>(wgt, wT);
  if (ws_size >= WS_NEED) {
    k_woprep<<<32, 256, 0, stream>>>(ow, mw, wTo);
    k_xprep<<<4096, 256, 0, stream>>>((const float4*)x, (uint4*)xhp);
    k_offmod_m<<<512, 256, 0, stream>>>(xhp, wTo, ob, mb, dyb, dxb, mskb);
    k_main_h<<<512, 512, 0, stream>>>(xhp, wT, dyb, dxb, mskb, out, psum, psq);
  } else {
    k_offmod_fb<<<512, 512, 0, stream>>>(x, ow, ob, mw, mb, dyb, dxb, mskb);
    k_main_f32<<<512, 512, 0, stream>>>(x, wT, dyb, dxb, mskb, out, psum, psq);
  }
  k_stats<<<256, 64, 0, stream>>>(psum, psq, gamma, beta, scale, shift);
  k_bnrelu<<<8192, 256, 0, stream>>>(out, scale, shift);
}